// Round 2
// baseline (826.715 us; speedup 1.0000x reference)
//
#include <hip/hip_runtime.h>
#include <cstdint>
#include <cstddef>

// Problem constants (B=4, S=2048, D=1024)
#define DD 1024
#define SSEQ 2048
#define NB 4
#define MROWS 8192          // B*S
#define FBINS 513           // rfft bins for N=1024
#define FPAD 520            // padded row stride (rows 64B-aligned)
#define NQKV 3072
#define NHID 4096

typedef _Float16 f16_t;
typedef _Float16 f16x8 __attribute__((ext_vector_type(8)));
typedef float f32x4 __attribute__((ext_vector_type(4)));

__device__ __forceinline__ float2 cmul(float2 a, float2 b) {
  return make_float2(a.x * b.x - a.y * b.y, a.x * b.y + a.y * b.x);
}

// ---------------------------------------------------------------------------
// Transpose + cast fp32 (K x N) -> fp16 (N x K)
// ---------------------------------------------------------------------------
__global__ __launch_bounds__(256) void transpose_cast_k(
    const float* __restrict__ W, f16_t* __restrict__ Wt, int K, int N) {
  __shared__ float tile[32][33];
  const int tx = threadIdx.x & 31, ty = threadIdx.x >> 5;  // 32 x 8
  const int n0 = blockIdx.x * 32, k0 = blockIdx.y * 32;
#pragma unroll
  for (int i = 0; i < 32; i += 8)
    tile[ty + i][tx] = W[(size_t)(k0 + ty + i) * N + n0 + tx];
  __syncthreads();
#pragma unroll
  for (int i = 0; i < 32; i += 8)
    Wt[(size_t)(n0 + ty + i) * K + k0 + tx] = (f16_t)tile[tx][ty + i];
}

// Transpose + split-cast fp32 (K x N) -> fp16 hi/lo pair (N x K)
__global__ __launch_bounds__(256) void transpose_cast2_k(
    const float* __restrict__ W, f16_t* __restrict__ WtH,
    f16_t* __restrict__ WtL, int K, int N) {
  __shared__ float tile[32][33];
  const int tx = threadIdx.x & 31, ty = threadIdx.x >> 5;  // 32 x 8
  const int n0 = blockIdx.x * 32, k0 = blockIdx.y * 32;
#pragma unroll
  for (int i = 0; i < 32; i += 8)
    tile[ty + i][tx] = W[(size_t)(k0 + ty + i) * N + n0 + tx];
  __syncthreads();
#pragma unroll
  for (int i = 0; i < 32; i += 8) {
    float val = tile[tx][ty + i];
    f16_t hi = (f16_t)val;
    f16_t lo = (f16_t)(val - (float)hi);
    size_t idx = (size_t)(n0 + ty + i) * K + k0 + tx;
    WtH[idx] = hi;
    WtL[idx] = lo;
  }
}

__global__ void concat3_k(const float* __restrict__ a, const float* __restrict__ b,
                          const float* __restrict__ c, float* __restrict__ o) {
  int i = blockIdx.x * 256 + threadIdx.x;
  if (i < 1024) o[i] = a[i];
  else if (i < 2048) o[i] = b[i - 1024];
  else if (i < 3072) o[i] = c[i - 2048];
}

// ---------------------------------------------------------------------------
// LayerNorm (fp32 in) -> split fp16 hi/lo.  One block per row of 1024.
// ---------------------------------------------------------------------------
__global__ __launch_bounds__(256) void ln_cast2_k(
    const float* __restrict__ x, const float* __restrict__ g,
    const float* __restrict__ b, f16_t* __restrict__ hH,
    f16_t* __restrict__ hL) {
  const int row = blockIdx.x, tid = threadIdx.x;
  __shared__ float red[8];
  const float* xr = x + (size_t)row * DD;
  float v[4], ls = 0.f, lq = 0.f;
#pragma unroll
  for (int i = 0; i < 4; ++i) {
    v[i] = xr[i * 256 + tid];
    ls += v[i];
    lq += v[i] * v[i];
  }
#pragma unroll
  for (int o = 32; o > 0; o >>= 1) {
    ls += __shfl_down(ls, o);
    lq += __shfl_down(lq, o);
  }
  const int lane = tid & 63, w = tid >> 6;
  if (lane == 0) { red[w] = ls; red[w + 4] = lq; }
  __syncthreads();
  const float S = red[0] + red[1] + red[2] + red[3];
  const float Q = red[4] + red[5] + red[6] + red[7];
  const float mean = S * (1.f / 1024.f);
  const float var = Q * (1.f / 1024.f) - mean * mean;
  const float rs = rsqrtf(var + 1e-5f);
#pragma unroll
  for (int i = 0; i < 4; ++i) {
    int n = i * 256 + tid;
    float val = (v[i] - mean) * rs * g[n] + b[n];
    f16_t hi = (f16_t)val;
    hH[(size_t)row * DD + n] = hi;
    hL[(size_t)row * DD + n] = (f16_t)(val - (float)hi);
  }
}

// ---------------------------------------------------------------------------
// Split-fp16 GEMM: C = (Ahi+Alo)(Bhi+Blo)^T + bias  (drops Alo*Blo, err~eps^2)
// fp32 accum.  Tiles 128x128x32, 4 waves (2x2), 4x4 of 16x16x32 MFMA x3 sets.
// LDS rows padded to 40 f16 (80B = 5*16B): b128-aligned, 4 tiles = 40 KiB.
// ---------------------------------------------------------------------------
__global__ __launch_bounds__(256, 2) void gemm_split_k(
    const f16_t* __restrict__ Ahi, const f16_t* __restrict__ Alo,
    const f16_t* __restrict__ Bhi, const f16_t* __restrict__ Blo,
    const float* __restrict__ bias, float* __restrict__ outF,
    int M, int N, int K) {
  __shared__ alignas(16) f16_t AsH[128 * 40];
  __shared__ alignas(16) f16_t AsL[128 * 40];
  __shared__ alignas(16) f16_t BsH[128 * 40];
  __shared__ alignas(16) f16_t BsL[128 * 40];
  const int tid = threadIdx.x;
  const int lane = tid & 63;
  const int w = tid >> 6;
  const int wm = w >> 1, wn = w & 1;
  const int bm = blockIdx.y * 128;
  const int bn = blockIdx.x * 128;

  f32x4 acc[4][4];
#pragma unroll
  for (int i = 0; i < 4; ++i)
#pragma unroll
    for (int j = 0; j < 4; ++j) acc[i][j] = (f32x4){0.f, 0.f, 0.f, 0.f};

  for (int kt = 0; kt < K; kt += 32) {
#pragma unroll
    for (int i = 0; i < 2; ++i) {
      int c = i * 256 + tid;      // 0..511 chunks of 16B (128 rows x 4 groups)
      int row = c >> 2;           // 0..127
      int g = c & 3;              // 16B group within 64B row
      size_t ga = (size_t)(bm + row) * K + kt + g * 8;
      *(uint4*)(&AsH[row * 40 + g * 8]) = *(const uint4*)(Ahi + ga);
      *(uint4*)(&AsL[row * 40 + g * 8]) = *(const uint4*)(Alo + ga);
      size_t gb = (size_t)(bn + row) * K + kt + g * 8;
      *(uint4*)(&BsH[row * 40 + g * 8]) = *(const uint4*)(Bhi + gb);
      *(uint4*)(&BsL[row * 40 + g * 8]) = *(const uint4*)(Blo + gb);
    }
    __syncthreads();
    {
      const int col = (lane >> 4) * 8;
      f16x8 ah[4], al[4], bh[4], bl[4];
#pragma unroll
      for (int mt = 0; mt < 4; ++mt) {
        int m = wm * 64 + mt * 16 + (lane & 15);
        ah[mt] = *(const f16x8*)(&AsH[m * 40 + col]);
        al[mt] = *(const f16x8*)(&AsL[m * 40 + col]);
      }
#pragma unroll
      for (int nt = 0; nt < 4; ++nt) {
        int n = wn * 64 + nt * 16 + (lane & 15);
        bh[nt] = *(const f16x8*)(&BsH[n * 40 + col]);
        bl[nt] = *(const f16x8*)(&BsL[n * 40 + col]);
      }
#pragma unroll
      for (int mt = 0; mt < 4; ++mt)
#pragma unroll
        for (int nt = 0; nt < 4; ++nt) {
          acc[mt][nt] = __builtin_amdgcn_mfma_f32_16x16x32_f16(
              ah[mt], bh[nt], acc[mt][nt], 0, 0, 0);
          acc[mt][nt] = __builtin_amdgcn_mfma_f32_16x16x32_f16(
              al[mt], bh[nt], acc[mt][nt], 0, 0, 0);
          acc[mt][nt] = __builtin_amdgcn_mfma_f32_16x16x32_f16(
              ah[mt], bl[nt], acc[mt][nt], 0, 0, 0);
        }
    }
    __syncthreads();
  }

  const int q = lane >> 4;
  const int cn = lane & 15;
#pragma unroll
  for (int mt = 0; mt < 4; ++mt) {
#pragma unroll
    for (int nt = 0; nt < 4; ++nt) {
      const int gcol = bn + wn * 64 + nt * 16 + cn;
      const float bv = bias[gcol];
      const int grow0 = bm + wm * 64 + mt * 16 + q * 4;
#pragma unroll
      for (int i = 0; i < 4; ++i) {
        size_t idx = (size_t)(grow0 + i) * N + gcol;
        outF[idx] = acc[mt][nt][i] + bv;
      }
    }
  }
}

// ---------------------------------------------------------------------------
// Plain fp16 GEMM: C(M,N) = A(M,K) @ Bt(N,K)^T + bias.
// EPI 1: gelu(exact) -> fp16.  EPI 2: +resid -> fp32.
// Tiles 128x128x64, LDS rows padded to 72 f16.
// ---------------------------------------------------------------------------
template <int EPI>
__global__ __launch_bounds__(256, 2) void gemm_bt_k(
    const f16_t* __restrict__ A, const f16_t* __restrict__ Bt,
    const float* __restrict__ bias, const float* __restrict__ resid,
    float* __restrict__ outF, f16_t* __restrict__ outH, int M, int N, int K) {
  __shared__ alignas(16) f16_t As[128 * 72];
  __shared__ alignas(16) f16_t Bs[128 * 72];
  const int tid = threadIdx.x;
  const int lane = tid & 63;
  const int w = tid >> 6;
  const int wm = w >> 1, wn = w & 1;
  const int bm = blockIdx.y * 128;
  const int bn = blockIdx.x * 128;

  f32x4 acc[4][4];
#pragma unroll
  for (int i = 0; i < 4; ++i)
#pragma unroll
    for (int j = 0; j < 4; ++j) acc[i][j] = (f32x4){0.f, 0.f, 0.f, 0.f};

  for (int kt = 0; kt < K; kt += 64) {
#pragma unroll
    for (int i = 0; i < 4; ++i) {
      int c = i * 256 + tid;      // 0..1023 chunk of 16B
      int row = c >> 3;           // 0..127
      int g = c & 7;              // 16B group within 128B row
      const f16_t* ga = A + (size_t)(bm + row) * K + kt + g * 8;
      *(uint4*)(&As[row * 72 + g * 8]) = *(const uint4*)ga;
      const f16_t* gb = Bt + (size_t)(bn + row) * K + kt + g * 8;
      *(uint4*)(&Bs[row * 72 + g * 8]) = *(const uint4*)gb;
    }
    __syncthreads();
#pragma unroll
    for (int ks = 0; ks < 2; ++ks) {
      f16x8 af[4], bfv[4];
      const int col = ks * 32 + (lane >> 4) * 8;
#pragma unroll
      for (int mt = 0; mt < 4; ++mt) {
        int m = wm * 64 + mt * 16 + (lane & 15);
        af[mt] = *(const f16x8*)(&As[m * 72 + col]);
      }
#pragma unroll
      for (int nt = 0; nt < 4; ++nt) {
        int n = wn * 64 + nt * 16 + (lane & 15);
        bfv[nt] = *(const f16x8*)(&Bs[n * 72 + col]);
      }
#pragma unroll
      for (int mt = 0; mt < 4; ++mt)
#pragma unroll
        for (int nt = 0; nt < 4; ++nt)
          acc[mt][nt] = __builtin_amdgcn_mfma_f32_16x16x32_f16(
              af[mt], bfv[nt], acc[mt][nt], 0, 0, 0);
    }
    __syncthreads();
  }

  // epilogue: C row = quad*4 + reg, col = lane&15  (verified m89/m91 layout)
  const int q = lane >> 4;
  const int cn = lane & 15;
#pragma unroll
  for (int mt = 0; mt < 4; ++mt) {
#pragma unroll
    for (int nt = 0; nt < 4; ++nt) {
      const int gcol = bn + wn * 64 + nt * 16 + cn;
      const float bv = bias[gcol];
      const int grow0 = bm + wm * 64 + mt * 16 + q * 4;
#pragma unroll
      for (int i = 0; i < 4; ++i) {
        float val = acc[mt][nt][i] + bv;
        size_t idx = (size_t)(grow0 + i) * N + gcol;
        if (EPI == 1) {
          float ge = 0.5f * val * (1.0f + erff(val * 0.70710678118654752f));
          outH[idx] = (f16_t)ge;
        } else {
          outF[idx] = val + resid[idx];
        }
      }
    }
  }
}

// ---------------------------------------------------------------------------
// Per-row: FFT(q_pre), FFT(k_pre), FFT(v_pre) (len 1024, fp32), normalize
// magnitudes (unit_projection in freq domain), emit Fq half-spectrum and
// P = Fk .* Fv half-spectrum.  Stockham radix-2, LDS ping-pong.
// ---------------------------------------------------------------------------
__global__ __launch_bounds__(256) void fftnorm_k(
    const float* __restrict__ qkv, float2* __restrict__ Fq,
    float2* __restrict__ P) {
  __shared__ float2 tw[512];
  __shared__ float2 bufA[1024];
  __shared__ float2 bufB[1024];
  __shared__ float2 hold[516];
  const int tid = threadIdx.x;
  const int row = blockIdx.x;

  for (int t = tid; t < 512; t += 256) {
    float ang = -6.2831853071795864769f * (float)t * (1.0f / 1024.0f);
    tw[t] = make_float2(cosf(ang), sinf(ang));
  }

  for (int which = 0; which < 3; ++which) {
    const float* src = qkv + (size_t)row * NQKV + which * DD;
    for (int t = tid; t < 1024; t += 256) bufA[t] = make_float2(src[t], 0.f);
    __syncthreads();

    float2* s = bufA;
    float2* d = bufB;
    for (int m = 1; m < 1024; m <<= 1) {
#pragma unroll
      for (int r2 = 0; r2 < 2; ++r2) {
        int u = tid + r2 * 256;
        int k = u & (m - 1);
        int jm = u - k;
        float2 c0 = s[u];
        float2 c1 = s[u + 512];
        float2 wt = tw[jm];
        float2 su = make_float2(c0.x + c1.x, c0.y + c1.y);
        float2 df = make_float2(c0.x - c1.x, c0.y - c1.y);
        float2 pr = cmul(wt, df);
        d[2 * jm + k] = su;
        d[2 * jm + k + m] = pr;
      }
      __syncthreads();
      float2* tmp = s; s = d; d = tmp;
    }
    // result back in bufA after 10 swaps
    for (int t = tid; t <= 512; t += 256) {
      float2 f = s[t];
      float mag = sqrtf(f.x * f.x + f.y * f.y);
      float inv = 1.0f / fmaxf(mag, 1e-8f);
      float2 fn = make_float2(f.x * inv, f.y * inv);
      if (which == 0) {
        Fq[(size_t)row * FPAD + t] = fn;
      } else if (which == 1) {
        hold[t] = fn;
      } else {
        float2 a = hold[t];
        P[(size_t)row * FPAD + t] = cmul(a, fn);
      }
    }
    __syncthreads();
  }
}

// ---------------------------------------------------------------------------
// In-place inclusive prefix sum of P over S per (batch, bin).
// ---------------------------------------------------------------------------
__global__ __launch_bounds__(256) void scan_k(float2* __restrict__ P) {
  const int bidx = blockIdx.x;        // 0..11 : b*3 + fchunk
  const int b = bidx / 3, fc = bidx % 3;
  const int f = fc * 256 + threadIdx.x;
  if (f > 512) return;
  float2 acc = make_float2(0.f, 0.f);
  const size_t base = (size_t)b * SSEQ * FPAD + f;
  for (int s0 = 0; s0 < SSEQ; s0 += 8) {
    float2 v[8];
#pragma unroll
    for (int i = 0; i < 8; ++i) v[i] = P[base + (size_t)(s0 + i) * FPAD];
#pragma unroll
    for (int i = 0; i < 8; ++i) {
      acc.x += v[i].x;
      acc.y += v[i].y;
      P[base + (size_t)(s0 + i) * FPAD] = acc;
    }
  }
}

// ---------------------------------------------------------------------------
// Per-row: M = Scum .* conj(Fq); mixed = irfft(M); x2 = x + mixed (fp32 out);
// h2 = LN2(x2) -> fp16.
// ---------------------------------------------------------------------------
__global__ __launch_bounds__(256) void unbind_ln2_k(
    const float2* __restrict__ Scum, const float2* __restrict__ Fq,
    const float* __restrict__ x, float* __restrict__ x2out,
    f16_t* __restrict__ h2, const float* __restrict__ g2,
    const float* __restrict__ b2) {
  __shared__ float2 tw[512];
  __shared__ float2 bufA[1024];
  __shared__ float2 bufB[1024];
  __shared__ float red[8];
  const int tid = threadIdx.x;
  const int row = blockIdx.x;

  for (int t = tid; t < 512; t += 256) {
    float ang = 6.2831853071795864769f * (float)t * (1.0f / 1024.0f);
    tw[t] = make_float2(cosf(ang), sinf(ang));  // conj twiddles (inverse)
  }
  // build hermitian full spectrum of M = Scum * conj(Fq)
  for (int t = tid; t <= 512; t += 256) {
    float2 sc = Scum[(size_t)row * FPAD + t];
    float2 fq = Fq[(size_t)row * FPAD + t];
    float2 Mv = make_float2(sc.x * fq.x + sc.y * fq.y, sc.y * fq.x - sc.x * fq.y);
    bufA[t] = Mv;
    if (t >= 1 && t < 512) bufA[1024 - t] = make_float2(Mv.x, -Mv.y);
  }
  __syncthreads();

  float2* s = bufA;
  float2* d = bufB;
  for (int m = 1; m < 1024; m <<= 1) {
#pragma unroll
    for (int r2 = 0; r2 < 2; ++r2) {
      int u = tid + r2 * 256;
      int k = u & (m - 1);
      int jm = u - k;
      float2 c0 = s[u];
      float2 c1 = s[u + 512];
      float2 wt = tw[jm];
      float2 su = make_float2(c0.x + c1.x, c0.y + c1.y);
      float2 df = make_float2(c0.x - c1.x, c0.y - c1.y);
      float2 pr = cmul(wt, df);
      d[2 * jm + k] = su;
      d[2 * jm + k + m] = pr;
    }
    __syncthreads();
    float2* tmp = s; s = d; d = tmp;
  }

  const float* xr = x + (size_t)row * DD;
  float v[4], ls = 0.f, lq = 0.f;
#pragma unroll
  for (int i = 0; i < 4; ++i) {
    int n = i * 256 + tid;
    float val = xr[n] + s[n].x * (1.0f / 1024.0f);
    x2out[(size_t)row * DD + n] = val;
    v[i] = val;
    ls += val;
    lq += val * val;
  }
#pragma unroll
  for (int o = 32; o > 0; o >>= 1) {
    ls += __shfl_down(ls, o);
    lq += __shfl_down(lq, o);
  }
  const int lane = tid & 63, w = tid >> 6;
  if (lane == 0) { red[w] = ls; red[w + 4] = lq; }
  __syncthreads();
  const float S = red[0] + red[1] + red[2] + red[3];
  const float Q = red[4] + red[5] + red[6] + red[7];
  const float mean = S * (1.f / 1024.f);
  const float var = Q * (1.f / 1024.f) - mean * mean;
  const float rs = rsqrtf(var + 1e-5f);
  f16_t* hr = h2 + (size_t)row * DD;
#pragma unroll
  for (int i = 0; i < 4; ++i) {
    int n = i * 256 + tid;
    hr[n] = (f16_t)((v[i] - mean) * rs * g2[n] + b2[n]);
  }
}

// ---------------------------------------------------------------------------
extern "C" void kernel_launch(void* const* d_in, const int* in_sizes, int n_in,
                              void* d_out, int out_size, void* d_ws,
                              size_t ws_size, hipStream_t stream) {
  const float* x     = (const float*)d_in[0];
  const float* Wq    = (const float*)d_in[1];
  const float* bq    = (const float*)d_in[2];
  const float* Wk    = (const float*)d_in[3];
  const float* bk    = (const float*)d_in[4];
  const float* Wv    = (const float*)d_in[5];
  const float* bv    = (const float*)d_in[6];
  const float* ln1_g = (const float*)d_in[7];
  const float* ln1_b = (const float*)d_in[8];
  const float* ln2_g = (const float*)d_in[9];
  const float* ln2_b = (const float*)d_in[10];
  const float* W1    = (const float*)d_in[11];
  const float* b1    = (const float*)d_in[12];
  const float* W2    = (const float*)d_in[13];
  const float* b2    = (const float*)d_in[14];
  float* out = (float*)d_out;

  char* p = (char*)d_ws;
  auto take = [&](size_t bytes) {
    char* r = p;
    p += (bytes + 255) & ~(size_t)255;
    return r;
  };
  f16_t* WqkvH = (f16_t*)take((size_t)NQKV * DD * sizeof(f16_t));
  f16_t* WqkvL = (f16_t*)take((size_t)NQKV * DD * sizeof(f16_t));
  f16_t* W1T   = (f16_t*)take((size_t)NHID * DD * sizeof(f16_t));
  f16_t* W2T   = (f16_t*)take((size_t)DD * NHID * sizeof(f16_t));
  float* biasq = (float*)take((size_t)NQKV * sizeof(float));
  f16_t* hbuf  = (f16_t*)take((size_t)MROWS * DD * sizeof(f16_t));   // h_hi, then h2
  char*  big   = take((size_t)MROWS * NQKV * sizeof(float));         // qkv_pre, then mlp1
  float2* Fqb  = (float2*)take((size_t)MROWS * FPAD * sizeof(float2));
  float2* Pb   = (float2*)take((size_t)MROWS * FPAD * sizeof(float2));
  float* x2    = (float*)take((size_t)MROWS * DD * sizeof(float));
  float* qkv_pre = (float*)big;
  f16_t* mlp1    = (f16_t*)big;
  // h_lo aliases x2: h_lo is consumed by the QKV gemm, x2 is first written
  // later (unbind_ln2_k) — lifetimes are disjoint in stream order.
  f16_t* hlo   = (f16_t*)x2;

  // weights -> transposed fp16 (QKV: hi/lo split pair)
  transpose_cast2_k<<<dim3(32, 32), 256, 0, stream>>>(Wq, WqkvH, WqkvL, DD, DD);
  transpose_cast2_k<<<dim3(32, 32), 256, 0, stream>>>(
      Wk, WqkvH + (size_t)1024 * DD, WqkvL + (size_t)1024 * DD, DD, DD);
  transpose_cast2_k<<<dim3(32, 32), 256, 0, stream>>>(
      Wv, WqkvH + (size_t)2048 * DD, WqkvL + (size_t)2048 * DD, DD, DD);
  transpose_cast_k<<<dim3(128, 32), 256, 0, stream>>>(W1, W1T, DD, NHID);
  transpose_cast_k<<<dim3(32, 128), 256, 0, stream>>>(W2, W2T, NHID, DD);
  concat3_k<<<12, 256, 0, stream>>>(bq, bk, bv, biasq);

  // h = LN1(x) -> hi/lo fp16 pair
  ln_cast2_k<<<MROWS, 256, 0, stream>>>(x, ln1_g, ln1_b, hbuf, hlo);

  // qkv_pre = h @ [Wq|Wk|Wv] + bias   (split-fp16, fp32-accurate)
  gemm_split_k<<<dim3(NQKV / 128, MROWS / 128), 256, 0, stream>>>(
      hbuf, hlo, WqkvH, WqkvL, biasq, qkv_pre, MROWS, NQKV, DD);

  // frequency-domain unit projection + bind product
  fftnorm_k<<<MROWS, 256, 0, stream>>>(qkv_pre, Fqb, Pb);

  // causal prefix sum over S (in freq domain)
  scan_k<<<12, 256, 0, stream>>>(Pb);

  // unbind + residual + LN2  (writes x2 — clobbers hlo alias, now dead)
  unbind_ln2_k<<<MROWS, 256, 0, stream>>>(Pb, Fqb, x, x2, hbuf, ln2_g, ln2_b);

  // mlp1 = gelu(h2 @ W1 + b1)
  gemm_bt_k<1><<<dim3(NHID / 128, MROWS / 128), 256, 0, stream>>>(
      hbuf, W1T, b1, nullptr, nullptr, mlp1, MROWS, NHID, DD);

  // out = x2 + mlp1 @ W2 + b2
  gemm_bt_k<2><<<dim3(DD / 128, MROWS / 128), 256, 0, stream>>>(
      mlp1, W2T, b2, x2, out, nullptr, MROWS, DD, NHID);
}

// Round 3
// 736.037 us; speedup vs baseline: 1.1232x; 1.1232x over previous
//
#include <hip/hip_runtime.h>
#include <cstdint>
#include <cstddef>

// Problem constants (B=4, S=2048, D=1024)
#define DD 1024
#define SSEQ 2048
#define NB 4
#define MROWS 8192          // B*S
#define FBINS 513           // rfft bins for N=1024
#define FPAD 520            // padded row stride for Fq/P buffers
#define NQKV 3200           // 3 * 1056 (padded complex cols) rounded to 25*128
#define WFP 1056            // per-projection padded complex column count
#define NHID 4096
#define NCHUNK 64           // scan chunks over S
#define SCHUNK 32           // S per chunk

typedef _Float16 f16_t;
typedef _Float16 f16x8 __attribute__((ext_vector_type(8)));
typedef float f32x4 __attribute__((ext_vector_type(4)));

__device__ __forceinline__ float2 cmul(float2 a, float2 b) {
  return make_float2(a.x * b.x - a.y * b.y, a.x * b.y + a.y * b.x);
}

// 1024-pt complex FFT over LDS ping-pong buffers; result lands back in bufA.
// tw must hold 512 twiddles of the desired sign. Caller must __syncthreads()
// after filling tw/bufA and before calling.
__device__ __forceinline__ void fft1024(float2* bufA, float2* bufB,
                                        const float2* tw, int tid) {
  float2* s = bufA;
  float2* d = bufB;
  for (int m = 1; m < 1024; m <<= 1) {
#pragma unroll
    for (int r2 = 0; r2 < 2; ++r2) {
      int u = tid + r2 * 256;
      int k = u & (m - 1);
      int jm = u - k;
      float2 c0 = s[u];
      float2 c1 = s[u + 512];
      float2 wt = tw[jm];
      float2 su = make_float2(c0.x + c1.x, c0.y + c1.y);
      float2 df = make_float2(c0.x - c1.x, c0.y - c1.y);
      float2 pr = cmul(wt, df);
      d[2 * jm + k] = su;
      d[2 * jm + k + m] = pr;
    }
    __syncthreads();
    float2* tmp = s; s = d; d = tmp;
  }
}

// ---------------------------------------------------------------------------
// Weight-row FFT: WfAll[p][k][j] = interleaved Re/Im of rfft(W_p[k, :]).
// j in [0,1026) data, [1026,1056) zero pad.  One block per (p,k).
// ---------------------------------------------------------------------------
__global__ __launch_bounds__(256) void wfft_k(
    const float* __restrict__ Wq, const float* __restrict__ Wk,
    const float* __restrict__ Wv, float* __restrict__ WfAll) {
  __shared__ float2 tw[512];
  __shared__ float2 bufA[1024];
  __shared__ float2 bufB[1024];
  const int tid = threadIdx.x;
  const int p = blockIdx.x >> 10, k = blockIdx.x & 1023;
  const float* W = (p == 0) ? Wq : ((p == 1) ? Wk : Wv);
  for (int t = tid; t < 512; t += 256) {
    float ang = -6.2831853071795864769f * (float)t * (1.0f / 1024.0f);
    tw[t] = make_float2(cosf(ang), sinf(ang));
  }
  const float* src = W + (size_t)k * DD;
  for (int t = tid; t < 1024; t += 256) bufA[t] = make_float2(src[t], 0.f);
  __syncthreads();
  fft1024(bufA, bufB, tw, tid);
  float* dst = WfAll + ((size_t)p * DD + k) * WFP;
  for (int t = tid; t <= 512; t += 256) {
    float2 f = bufA[t];
    dst[2 * t] = f.x;
    dst[2 * t + 1] = f.y;   // max index 1025 < 1056
  }
  for (int j = 1026 + tid; j < WFP; j += 256) dst[j] = 0.f;
}

// ---------------------------------------------------------------------------
// Bias FFT: biasC[p*WFP + 2f + c] = rfft(bias_p)[f] components; pads zeroed.
// Blocks 0..2 = projections; block 3 zeros biasC[3168..3200).
// ---------------------------------------------------------------------------
__global__ __launch_bounds__(256) void bfft_k(
    const float* __restrict__ bq, const float* __restrict__ bk,
    const float* __restrict__ bv, float* __restrict__ biasC) {
  __shared__ float2 tw[512];
  __shared__ float2 bufA[1024];
  __shared__ float2 bufB[1024];
  const int tid = threadIdx.x;
  const int p = blockIdx.x;
  if (p == 3) {
    for (int j = 3 * WFP + tid; j < NQKV; j += 256) biasC[j] = 0.f;
    return;
  }
  const float* bsrc = (p == 0) ? bq : ((p == 1) ? bk : bv);
  for (int t = tid; t < 512; t += 256) {
    float ang = -6.2831853071795864769f * (float)t * (1.0f / 1024.0f);
    tw[t] = make_float2(cosf(ang), sinf(ang));
  }
  for (int t = tid; t < 1024; t += 256) bufA[t] = make_float2(bsrc[t], 0.f);
  __syncthreads();
  fft1024(bufA, bufB, tw, tid);
  float* dst = biasC + (size_t)p * WFP;
  for (int t = tid; t <= 512; t += 256) {
    float2 f = bufA[t];
    dst[2 * t] = f.x;
    dst[2 * t + 1] = f.y;
  }
  for (int j = 1026 + tid; j < WFP; j += 256) dst[j] = 0.f;
}

// ---------------------------------------------------------------------------
// Transpose + cast fp32 (K x N) -> fp16 (N x K)
// ---------------------------------------------------------------------------
__global__ __launch_bounds__(256) void transpose_cast_k(
    const float* __restrict__ W, f16_t* __restrict__ Wt, int K, int N) {
  __shared__ float tile[32][33];
  const int tx = threadIdx.x & 31, ty = threadIdx.x >> 5;  // 32 x 8
  const int n0 = blockIdx.x * 32, k0 = blockIdx.y * 32;
#pragma unroll
  for (int i = 0; i < 32; i += 8)
    tile[ty + i][tx] = W[(size_t)(k0 + ty + i) * N + n0 + tx];
  __syncthreads();
#pragma unroll
  for (int i = 0; i < 32; i += 8)
    Wt[(size_t)(n0 + ty + i) * K + k0 + tx] = (f16_t)tile[tx][ty + i];
}

// Transpose + split-cast fp32 (K x N) -> fp16 hi/lo pair (N x K)
__global__ __launch_bounds__(256) void transpose_cast2_k(
    const float* __restrict__ W, f16_t* __restrict__ WtH,
    f16_t* __restrict__ WtL, int K, int N) {
  __shared__ float tile[32][33];
  const int tx = threadIdx.x & 31, ty = threadIdx.x >> 5;  // 32 x 8
  const int n0 = blockIdx.x * 32, k0 = blockIdx.y * 32;
#pragma unroll
  for (int i = 0; i < 32; i += 8)
    tile[ty + i][tx] = W[(size_t)(k0 + ty + i) * N + n0 + tx];
  __syncthreads();
#pragma unroll
  for (int i = 0; i < 32; i += 8) {
    float val = tile[tx][ty + i];
    f16_t hi = (f16_t)val;
    f16_t lo = (f16_t)(val - (float)hi);
    size_t idx = (size_t)(n0 + ty + i) * K + k0 + tx;
    WtH[idx] = hi;
    WtL[idx] = lo;
  }
}

// Zero Bt pad rows [3168, 3200) for both hi/lo.
__global__ void zeropad_bt_k(f16_t* __restrict__ BtH, f16_t* __restrict__ BtL) {
  // 32 rows x 1024 cols = 32768 elems; grid 128 x 256
  int i = blockIdx.x * 256 + threadIdx.x;
  size_t base = (size_t)(3 * WFP) * DD + i;
  BtH[base] = (f16_t)0.f;
  BtL[base] = (f16_t)0.f;
}

// ---------------------------------------------------------------------------
// LayerNorm (fp32 in) -> split fp16 hi/lo.  One block per row of 1024.
// ---------------------------------------------------------------------------
__global__ __launch_bounds__(256) void ln_cast2_k(
    const float* __restrict__ x, const float* __restrict__ g,
    const float* __restrict__ b, f16_t* __restrict__ hH,
    f16_t* __restrict__ hL) {
  const int row = blockIdx.x, tid = threadIdx.x;
  __shared__ float red[8];
  const float* xr = x + (size_t)row * DD;
  float v[4], ls = 0.f, lq = 0.f;
#pragma unroll
  for (int i = 0; i < 4; ++i) {
    v[i] = xr[i * 256 + tid];
    ls += v[i];
    lq += v[i] * v[i];
  }
#pragma unroll
  for (int o = 32; o > 0; o >>= 1) {
    ls += __shfl_down(ls, o);
    lq += __shfl_down(lq, o);
  }
  const int lane = tid & 63, w = tid >> 6;
  if (lane == 0) { red[w] = ls; red[w + 4] = lq; }
  __syncthreads();
  const float S = red[0] + red[1] + red[2] + red[3];
  const float Q = red[4] + red[5] + red[6] + red[7];
  const float mean = S * (1.f / 1024.f);
  const float var = Q * (1.f / 1024.f) - mean * mean;
  const float rs = rsqrtf(var + 1e-5f);
#pragma unroll
  for (int i = 0; i < 4; ++i) {
    int n = i * 256 + tid;
    float val = (v[i] - mean) * rs * g[n] + b[n];
    f16_t hi = (f16_t)val;
    hH[(size_t)row * DD + n] = hi;
    hL[(size_t)row * DD + n] = (f16_t)(val - (float)hi);
  }
}

// ---------------------------------------------------------------------------
// Split-fp16 GEMM: C = (Ahi+Alo)(Bhi+Blo)^T + bias  (drops Alo*Blo, err~eps^2)
// Tiles 128x128x32, LDS rows padded to 40 f16.
// ---------------------------------------------------------------------------
__global__ __launch_bounds__(256, 2) void gemm_split_k(
    const f16_t* __restrict__ Ahi, const f16_t* __restrict__ Alo,
    const f16_t* __restrict__ Bhi, const f16_t* __restrict__ Blo,
    const float* __restrict__ bias, float* __restrict__ outF,
    int M, int N, int K) {
  __shared__ alignas(16) f16_t AsH[128 * 40];
  __shared__ alignas(16) f16_t AsL[128 * 40];
  __shared__ alignas(16) f16_t BsH[128 * 40];
  __shared__ alignas(16) f16_t BsL[128 * 40];
  const int tid = threadIdx.x;
  const int lane = tid & 63;
  const int w = tid >> 6;
  const int wm = w >> 1, wn = w & 1;
  const int bm = blockIdx.y * 128;
  const int bn = blockIdx.x * 128;

  f32x4 acc[4][4];
#pragma unroll
  for (int i = 0; i < 4; ++i)
#pragma unroll
    for (int j = 0; j < 4; ++j) acc[i][j] = (f32x4){0.f, 0.f, 0.f, 0.f};

  for (int kt = 0; kt < K; kt += 32) {
#pragma unroll
    for (int i = 0; i < 2; ++i) {
      int c = i * 256 + tid;      // 0..511 chunks of 16B (128 rows x 4 groups)
      int row = c >> 2;           // 0..127
      int g = c & 3;              // 16B group within 64B row
      size_t ga = (size_t)(bm + row) * K + kt + g * 8;
      *(uint4*)(&AsH[row * 40 + g * 8]) = *(const uint4*)(Ahi + ga);
      *(uint4*)(&AsL[row * 40 + g * 8]) = *(const uint4*)(Alo + ga);
      size_t gb = (size_t)(bn + row) * K + kt + g * 8;
      *(uint4*)(&BsH[row * 40 + g * 8]) = *(const uint4*)(Bhi + gb);
      *(uint4*)(&BsL[row * 40 + g * 8]) = *(const uint4*)(Blo + gb);
    }
    __syncthreads();
    {
      const int col = (lane >> 4) * 8;
      f16x8 ah[4], al[4], bh[4], bl[4];
#pragma unroll
      for (int mt = 0; mt < 4; ++mt) {
        int m = wm * 64 + mt * 16 + (lane & 15);
        ah[mt] = *(const f16x8*)(&AsH[m * 40 + col]);
        al[mt] = *(const f16x8*)(&AsL[m * 40 + col]);
      }
#pragma unroll
      for (int nt = 0; nt < 4; ++nt) {
        int n = wn * 64 + nt * 16 + (lane & 15);
        bh[nt] = *(const f16x8*)(&BsH[n * 40 + col]);
        bl[nt] = *(const f16x8*)(&BsL[n * 40 + col]);
      }
#pragma unroll
      for (int mt = 0; mt < 4; ++mt)
#pragma unroll
        for (int nt = 0; nt < 4; ++nt) {
          acc[mt][nt] = __builtin_amdgcn_mfma_f32_16x16x32_f16(
              ah[mt], bh[nt], acc[mt][nt], 0, 0, 0);
          acc[mt][nt] = __builtin_amdgcn_mfma_f32_16x16x32_f16(
              al[mt], bh[nt], acc[mt][nt], 0, 0, 0);
          acc[mt][nt] = __builtin_amdgcn_mfma_f32_16x16x32_f16(
              ah[mt], bl[nt], acc[mt][nt], 0, 0, 0);
        }
    }
    __syncthreads();
  }

  const int q = lane >> 4;
  const int cn = lane & 15;
#pragma unroll
  for (int mt = 0; mt < 4; ++mt) {
#pragma unroll
    for (int nt = 0; nt < 4; ++nt) {
      const int gcol = bn + wn * 64 + nt * 16 + cn;
      const float bv = bias[gcol];
      const int grow0 = bm + wm * 64 + mt * 16 + q * 4;
#pragma unroll
      for (int i = 0; i < 4; ++i) {
        size_t idx = (size_t)(grow0 + i) * N + gcol;
        outF[idx] = acc[mt][nt][i] + bv;
      }
    }
  }
}

// ---------------------------------------------------------------------------
// Plain fp16 GEMM: C(M,N) = A(M,K) @ Bt(N,K)^T + bias.
// EPI 1: gelu(exact) -> fp16.  EPI 2: +resid -> fp32.
// ---------------------------------------------------------------------------
template <int EPI>
__global__ __launch_bounds__(256, 2) void gemm_bt_k(
    const f16_t* __restrict__ A, const f16_t* __restrict__ Bt,
    const float* __restrict__ bias, const float* __restrict__ resid,
    float* __restrict__ outF, f16_t* __restrict__ outH, int M, int N, int K) {
  __shared__ alignas(16) f16_t As[128 * 72];
  __shared__ alignas(16) f16_t Bs[128 * 72];
  const int tid = threadIdx.x;
  const int lane = tid & 63;
  const int w = tid >> 6;
  const int wm = w >> 1, wn = w & 1;
  const int bm = blockIdx.y * 128;
  const int bn = blockIdx.x * 128;

  f32x4 acc[4][4];
#pragma unroll
  for (int i = 0; i < 4; ++i)
#pragma unroll
    for (int j = 0; j < 4; ++j) acc[i][j] = (f32x4){0.f, 0.f, 0.f, 0.f};

  for (int kt = 0; kt < K; kt += 64) {
#pragma unroll
    for (int i = 0; i < 4; ++i) {
      int c = i * 256 + tid;
      int row = c >> 3;
      int g = c & 7;
      const f16_t* ga = A + (size_t)(bm + row) * K + kt + g * 8;
      *(uint4*)(&As[row * 72 + g * 8]) = *(const uint4*)ga;
      const f16_t* gb = Bt + (size_t)(bn + row) * K + kt + g * 8;
      *(uint4*)(&Bs[row * 72 + g * 8]) = *(const uint4*)gb;
    }
    __syncthreads();
#pragma unroll
    for (int ks = 0; ks < 2; ++ks) {
      f16x8 af[4], bfv[4];
      const int col = ks * 32 + (lane >> 4) * 8;
#pragma unroll
      for (int mt = 0; mt < 4; ++mt) {
        int m = wm * 64 + mt * 16 + (lane & 15);
        af[mt] = *(const f16x8*)(&As[m * 72 + col]);
      }
#pragma unroll
      for (int nt = 0; nt < 4; ++nt) {
        int n = wn * 64 + nt * 16 + (lane & 15);
        bfv[nt] = *(const f16x8*)(&Bs[n * 72 + col]);
      }
#pragma unroll
      for (int mt = 0; mt < 4; ++mt)
#pragma unroll
        for (int nt = 0; nt < 4; ++nt)
          acc[mt][nt] = __builtin_amdgcn_mfma_f32_16x16x32_f16(
              af[mt], bfv[nt], acc[mt][nt], 0, 0, 0);
    }
    __syncthreads();
  }

  const int q = lane >> 4;
  const int cn = lane & 15;
#pragma unroll
  for (int mt = 0; mt < 4; ++mt) {
#pragma unroll
    for (int nt = 0; nt < 4; ++nt) {
      const int gcol = bn + wn * 64 + nt * 16 + cn;
      const float bv = bias[gcol];
      const int grow0 = bm + wm * 64 + mt * 16 + q * 4;
#pragma unroll
      for (int i = 0; i < 4; ++i) {
        float val = acc[mt][nt][i] + bv;
        size_t idx = (size_t)(grow0 + i) * N + gcol;
        if (EPI == 1) {
          float ge = 0.5f * val * (1.0f + erff(val * 0.70710678118654752f));
          outH[idx] = (f16_t)ge;
        } else {
          outF[idx] = val + resid[idx];
        }
      }
    }
  }
}

// ---------------------------------------------------------------------------
// Elementwise: normalize q/k/v bins (unit_projection in freq domain),
// emit Fq and P = Fk .* Fv.  qkvF row = 3200 fp32 (Re/Im interleaved per proj).
// ---------------------------------------------------------------------------
__global__ __launch_bounds__(256) void normalize_k(
    const float* __restrict__ qkvF, float2* __restrict__ Fq,
    float2* __restrict__ P) {
  const int row = blockIdx.x, tid = threadIdx.x;
  const float2* r = (const float2*)(qkvF + (size_t)row * NQKV);  // 1600 float2
  for (int f = tid; f < FBINS; f += 256) {
    float2 q = r[f];
    float2 k = r[528 + f];    // WFP/2
    float2 v = r[1056 + f];   // 2*WFP/2
    float iq = 1.0f / fmaxf(sqrtf(q.x * q.x + q.y * q.y), 1e-8f);
    float ik = 1.0f / fmaxf(sqrtf(k.x * k.x + k.y * k.y), 1e-8f);
    float iv = 1.0f / fmaxf(sqrtf(v.x * v.x + v.y * v.y), 1e-8f);
    float2 qn = make_float2(q.x * iq, q.y * iq);
    float2 kn = make_float2(k.x * ik, k.y * ik);
    float2 vn = make_float2(v.x * iv, v.y * iv);
    Fq[(size_t)row * FPAD + f] = qn;
    P[(size_t)row * FPAD + f] = cmul(kn, vn);
  }
}

// ---------------------------------------------------------------------------
// 3-pass parallel prefix sum of P over S per (batch, bin).
// Pass 1: chunk totals.  Pass 2: exclusive scan of totals.  Pass 3: apply.
// ---------------------------------------------------------------------------
__global__ __launch_bounds__(256) void scan_pass1_k(
    const float2* __restrict__ P, float2* __restrict__ T) {
  const int b = blockIdx.x >> 6, sc = blockIdx.x & 63;
  const int s0 = sc * SCHUNK;
  for (int f = threadIdx.x; f < FBINS; f += 256) {
    float2 acc = make_float2(0.f, 0.f);
    size_t base = ((size_t)b * SSEQ + s0) * FPAD + f;
#pragma unroll 4
    for (int i = 0; i < SCHUNK; ++i) {
      float2 v = P[base + (size_t)i * FPAD];
      acc.x += v.x; acc.y += v.y;
    }
    T[((size_t)b * NCHUNK + sc) * FBINS + f] = acc;
  }
}

__global__ void scan_pass2_k(float2* __restrict__ T) {
  const int idx = blockIdx.x * 256 + threadIdx.x;
  if (idx >= NB * FBINS) return;
  const int b = idx / FBINS, f = idx % FBINS;
  float2 acc = make_float2(0.f, 0.f);
  for (int sc = 0; sc < NCHUNK; ++sc) {
    size_t a = ((size_t)b * NCHUNK + sc) * FBINS + f;
    float2 v = T[a];
    T[a] = acc;
    acc.x += v.x; acc.y += v.y;
  }
}

__global__ __launch_bounds__(256) void scan_pass3_k(
    float2* __restrict__ P, const float2* __restrict__ T) {
  const int b = blockIdx.x >> 6, sc = blockIdx.x & 63;
  const int s0 = sc * SCHUNK;
  for (int f = threadIdx.x; f < FBINS; f += 256) {
    float2 acc = T[((size_t)b * NCHUNK + sc) * FBINS + f];
    size_t base = ((size_t)b * SSEQ + s0) * FPAD + f;
#pragma unroll 4
    for (int i = 0; i < SCHUNK; ++i) {
      size_t a = base + (size_t)i * FPAD;
      float2 v = P[a];
      acc.x += v.x; acc.y += v.y;
      P[a] = acc;
    }
  }
}

// ---------------------------------------------------------------------------
// Per-row: M = Scum .* conj(Fq); mixed = irfft(M); x2 = x + mixed (fp32 out);
// h2 = LN2(x2) -> fp16.
// ---------------------------------------------------------------------------
__global__ __launch_bounds__(256) void unbind_ln2_k(
    const float2* __restrict__ Scum, const float2* __restrict__ Fq,
    const float* __restrict__ x, float* __restrict__ x2out,
    f16_t* __restrict__ h2, const float* __restrict__ g2,
    const float* __restrict__ b2) {
  __shared__ float2 tw[512];
  __shared__ float2 bufA[1024];
  __shared__ float2 bufB[1024];
  __shared__ float red[8];
  const int tid = threadIdx.x;
  const int row = blockIdx.x;

  for (int t = tid; t < 512; t += 256) {
    float ang = 6.2831853071795864769f * (float)t * (1.0f / 1024.0f);
    tw[t] = make_float2(cosf(ang), sinf(ang));  // inverse twiddles
  }
  for (int t = tid; t <= 512; t += 256) {
    float2 sc = Scum[(size_t)row * FPAD + t];
    float2 fq = Fq[(size_t)row * FPAD + t];
    float2 Mv = make_float2(sc.x * fq.x + sc.y * fq.y, sc.y * fq.x - sc.x * fq.y);
    bufA[t] = Mv;
    if (t >= 1 && t < 512) bufA[1024 - t] = make_float2(Mv.x, -Mv.y);
  }
  __syncthreads();
  fft1024(bufA, bufB, tw, tid);

  const float* xr = x + (size_t)row * DD;
  float v[4], ls = 0.f, lq = 0.f;
#pragma unroll
  for (int i = 0; i < 4; ++i) {
    int n = i * 256 + tid;
    float val = xr[n] + bufA[n].x * (1.0f / 1024.0f);
    x2out[(size_t)row * DD + n] = val;
    v[i] = val;
    ls += val;
    lq += val * val;
  }
#pragma unroll
  for (int o = 32; o > 0; o >>= 1) {
    ls += __shfl_down(ls, o);
    lq += __shfl_down(lq, o);
  }
  const int lane = tid & 63, w = tid >> 6;
  if (lane == 0) { red[w] = ls; red[w + 4] = lq; }
  __syncthreads();
  const float S = red[0] + red[1] + red[2] + red[3];
  const float Q = red[4] + red[5] + red[6] + red[7];
  const float mean = S * (1.f / 1024.f);
  const float var = Q * (1.f / 1024.f) - mean * mean;
  const float rs = rsqrtf(var + 1e-5f);
  f16_t* hr = h2 + (size_t)row * DD;
#pragma unroll
  for (int i = 0; i < 4; ++i) {
    int n = i * 256 + tid;
    hr[n] = (f16_t)((v[i] - mean) * rs * g2[n] + b2[n]);
  }
}

// ---------------------------------------------------------------------------
extern "C" void kernel_launch(void* const* d_in, const int* in_sizes, int n_in,
                              void* d_out, int out_size, void* d_ws,
                              size_t ws_size, hipStream_t stream) {
  const float* x     = (const float*)d_in[0];
  const float* Wq    = (const float*)d_in[1];
  const float* bq    = (const float*)d_in[2];
  const float* Wk    = (const float*)d_in[3];
  const float* bk    = (const float*)d_in[4];
  const float* Wv    = (const float*)d_in[5];
  const float* bv    = (const float*)d_in[6];
  const float* ln1_g = (const float*)d_in[7];
  const float* ln1_b = (const float*)d_in[8];
  const float* ln2_g = (const float*)d_in[9];
  const float* ln2_b = (const float*)d_in[10];
  const float* W1    = (const float*)d_in[11];
  const float* b1    = (const float*)d_in[12];
  const float* W2    = (const float*)d_in[13];
  const float* b2    = (const float*)d_in[14];
  float* out = (float*)d_out;

  char* p = (char*)d_ws;
  auto take = [&](size_t bytes) {
    char* r = p;
    p += (bytes + 255) & ~(size_t)255;
    return r;
  };
  f16_t* BtH   = (f16_t*)take((size_t)NQKV * DD * sizeof(f16_t));
  f16_t* BtL   = (f16_t*)take((size_t)NQKV * DD * sizeof(f16_t));
  f16_t* W1T   = (f16_t*)take((size_t)NHID * DD * sizeof(f16_t));
  f16_t* W2T   = (f16_t*)take((size_t)DD * NHID * sizeof(f16_t));
  float* biasC = (float*)take((size_t)NQKV * sizeof(float));
  f16_t* hbuf  = (f16_t*)take((size_t)MROWS * DD * sizeof(f16_t));   // h_hi, then h2
  char*  big   = take((size_t)MROWS * NQKV * sizeof(float));         // WfAll, qkvF, mlp1
  float2* Fqb  = (float2*)take((size_t)MROWS * FPAD * sizeof(float2));
  float2* Pb   = (float2*)take((size_t)MROWS * FPAD * sizeof(float2));
  float* x2    = (float*)take((size_t)MROWS * DD * sizeof(float));
  float2* Tch  = (float2*)take((size_t)NB * NCHUNK * FBINS * sizeof(float2));
  // time-disjoint aliases:
  float* WfAll   = (float*)big;   // consumed by transposes before gemm writes qkvF
  float* qkv_f   = (float*)big;   // bins from split GEMM
  f16_t* mlp1    = (f16_t*)big;   // gelu output, after qkv_f dead
  f16_t* hlo     = (f16_t*)x2;    // LN1 lo; dead before unbind writes x2

  // 1. FFT weight rows (fp32) -> WfAll[p][k][1056]
  wfft_k<<<3 * DD, 256, 0, stream>>>(Wq, Wk, Wv, WfAll);
  // 2. transpose + hi/lo split -> Bt (3*1056 x 1024), then zero pad rows
  for (int pp = 0; pp < 3; ++pp)
    transpose_cast2_k<<<dim3(WFP / 32, DD / 32), 256, 0, stream>>>(
        WfAll + (size_t)pp * DD * WFP,
        BtH + (size_t)pp * WFP * DD,
        BtL + (size_t)pp * WFP * DD, DD, WFP);
  zeropad_bt_k<<<128, 256, 0, stream>>>(BtH, BtL);
  // 3. FFT biases -> biasC (complex-component layout)
  bfft_k<<<4, 256, 0, stream>>>(bq, bk, bv, biasC);
  // 4. MLP weights -> transposed fp16
  transpose_cast_k<<<dim3(128, 32), 256, 0, stream>>>(W1, W1T, DD, NHID);
  transpose_cast_k<<<dim3(32, 128), 256, 0, stream>>>(W2, W2T, NHID, DD);

  // 5. h = LN1(x) -> hi/lo fp16 pair
  ln_cast2_k<<<MROWS, 256, 0, stream>>>(x, ln1_g, ln1_b, hbuf, hlo);

  // 6. Fourier bins directly: qkv_f = h @ rfft_rows(W)^T + rfft(bias)
  gemm_split_k<<<dim3(NQKV / 128, MROWS / 128), 256, 0, stream>>>(
      hbuf, hlo, BtH, BtL, biasC, qkv_f, MROWS, NQKV, DD);

  // 7. unit-normalize bins, P = Fk .* Fv
  normalize_k<<<MROWS, 256, 0, stream>>>(qkv_f, Fqb, Pb);

  // 8. causal prefix sum over S
  scan_pass1_k<<<NB * NCHUNK, 256, 0, stream>>>(Pb, Tch);
  scan_pass2_k<<<(NB * FBINS + 255) / 256, 256, 0, stream>>>(Tch);
  scan_pass3_k<<<NB * NCHUNK, 256, 0, stream>>>(Pb, Tch);

  // 9. unbind + residual + LN2  (writes x2 — hlo alias now dead)
  unbind_ln2_k<<<MROWS, 256, 0, stream>>>(Pb, Fqb, x, x2, hbuf, ln2_g, ln2_b);

  // 10. mlp1 = gelu(h2 @ W1 + b1)   (qkv_f dead -> reuse as mlp1)
  gemm_bt_k<1><<<dim3(NHID / 128, MROWS / 128), 256, 0, stream>>>(
      hbuf, W1T, b1, nullptr, nullptr, mlp1, MROWS, NHID, DD);

  // 11. out = x2 + mlp1 @ W2 + b2
  gemm_bt_k<2><<<dim3(DD / 128, MROWS / 128), 256, 0, stream>>>(
      mlp1, W2T, b2, x2, out, nullptr, MROWS, DD, NHID);
}

// Round 4
// 707.122 us; speedup vs baseline: 1.1691x; 1.0409x over previous
//
#include <hip/hip_runtime.h>
#include <cstdint>
#include <cstddef>

// Problem constants (B=4, S=2048, D=1024)
#define DD 1024
#define SSEQ 2048
#define NB 4
#define MROWS 8192          // B*S
#define FBINS 513           // rfft bins for N=1024
#define FPAD 520            // padded row stride for Scum buffer
#define NQKV 3200           // 3 * 1056 (padded complex cols) rounded to 25*128
#define WFP 1056            // per-projection padded complex column count
#define NHID 4096
#define NCHUNK 64           // scan chunks over S
#define SCHUNK 32           // S per chunk

typedef _Float16 f16_t;
typedef _Float16 f16x8 __attribute__((ext_vector_type(8)));
typedef float f32x4 __attribute__((ext_vector_type(4)));

__device__ __forceinline__ float2 cmul(float2 a, float2 b) {
  return make_float2(a.x * b.x - a.y * b.y, a.x * b.y + a.y * b.x);
}

// 1024-pt complex FFT over LDS ping-pong buffers; result lands back in bufA.
__device__ __forceinline__ void fft1024(float2* bufA, float2* bufB,
                                        const float2* tw, int tid) {
  float2* s = bufA;
  float2* d = bufB;
  for (int m = 1; m < 1024; m <<= 1) {
#pragma unroll
    for (int r2 = 0; r2 < 2; ++r2) {
      int u = tid + r2 * 256;
      int k = u & (m - 1);
      int jm = u - k;
      float2 c0 = s[u];
      float2 c1 = s[u + 512];
      float2 wt = tw[jm];
      float2 su = make_float2(c0.x + c1.x, c0.y + c1.y);
      float2 df = make_float2(c0.x - c1.x, c0.y - c1.y);
      float2 pr = cmul(wt, df);
      d[2 * jm + k] = su;
      d[2 * jm + k + m] = pr;
    }
    __syncthreads();
    float2* tmp = s; s = d; d = tmp;
  }
}

// ---------------------------------------------------------------------------
// Weight-row FFT: WfAll[p][k][j] = interleaved Re/Im of rfft(W_p[k, :]).
// ---------------------------------------------------------------------------
__global__ __launch_bounds__(256) void wfft_k(
    const float* __restrict__ Wq, const float* __restrict__ Wk,
    const float* __restrict__ Wv, float* __restrict__ WfAll) {
  __shared__ float2 tw[512];
  __shared__ float2 bufA[1024];
  __shared__ float2 bufB[1024];
  const int tid = threadIdx.x;
  const int p = blockIdx.x >> 10, k = blockIdx.x & 1023;
  const float* W = (p == 0) ? Wq : ((p == 1) ? Wk : Wv);
  for (int t = tid; t < 512; t += 256) {
    float ang = -6.2831853071795864769f * (float)t * (1.0f / 1024.0f);
    tw[t] = make_float2(cosf(ang), sinf(ang));
  }
  const float* src = W + (size_t)k * DD;
  for (int t = tid; t < 1024; t += 256) bufA[t] = make_float2(src[t], 0.f);
  __syncthreads();
  fft1024(bufA, bufB, tw, tid);
  float* dst = WfAll + ((size_t)p * DD + k) * WFP;
  for (int t = tid; t <= 512; t += 256) {
    float2 f = bufA[t];
    dst[2 * t] = f.x;
    dst[2 * t + 1] = f.y;
  }
  for (int j = 1026 + tid; j < WFP; j += 256) dst[j] = 0.f;
}

// ---------------------------------------------------------------------------
// Bias FFT (blocks 0..2) + pad-zero block 3.
// ---------------------------------------------------------------------------
__global__ __launch_bounds__(256) void bfft_k(
    const float* __restrict__ bq, const float* __restrict__ bk,
    const float* __restrict__ bv, float* __restrict__ biasC) {
  __shared__ float2 tw[512];
  __shared__ float2 bufA[1024];
  __shared__ float2 bufB[1024];
  const int tid = threadIdx.x;
  const int p = blockIdx.x;
  if (p == 3) {
    for (int j = 3 * WFP + tid; j < NQKV; j += 256) biasC[j] = 0.f;
    return;
  }
  const float* bsrc = (p == 0) ? bq : ((p == 1) ? bk : bv);
  for (int t = tid; t < 512; t += 256) {
    float ang = -6.2831853071795864769f * (float)t * (1.0f / 1024.0f);
    tw[t] = make_float2(cosf(ang), sinf(ang));
  }
  for (int t = tid; t < 1024; t += 256) bufA[t] = make_float2(bsrc[t], 0.f);
  __syncthreads();
  fft1024(bufA, bufB, tw, tid);
  float* dst = biasC + (size_t)p * WFP;
  for (int t = tid; t <= 512; t += 256) {
    float2 f = bufA[t];
    dst[2 * t] = f.x;
    dst[2 * t + 1] = f.y;
  }
  for (int j = 1026 + tid; j < WFP; j += 256) dst[j] = 0.f;
}

// ---------------------------------------------------------------------------
// Transpose + cast fp32 (K x N) -> fp16 (N x K)
// ---------------------------------------------------------------------------
__global__ __launch_bounds__(256) void transpose_cast_k(
    const float* __restrict__ W, f16_t* __restrict__ Wt, int K, int N) {
  __shared__ float tile[32][33];
  const int tx = threadIdx.x & 31, ty = threadIdx.x >> 5;  // 32 x 8
  const int n0 = blockIdx.x * 32, k0 = blockIdx.y * 32;
#pragma unroll
  for (int i = 0; i < 32; i += 8)
    tile[ty + i][tx] = W[(size_t)(k0 + ty + i) * N + n0 + tx];
  __syncthreads();
#pragma unroll
  for (int i = 0; i < 32; i += 8)
    Wt[(size_t)(n0 + ty + i) * K + k0 + tx] = (f16_t)tile[tx][ty + i];
}

// Transpose + split-cast fp32 (K x N) -> fp16 hi/lo pair (N x K)
__global__ __launch_bounds__(256) void transpose_cast2_k(
    const float* __restrict__ W, f16_t* __restrict__ WtH,
    f16_t* __restrict__ WtL, int K, int N) {
  __shared__ float tile[32][33];
  const int tx = threadIdx.x & 31, ty = threadIdx.x >> 5;  // 32 x 8
  const int n0 = blockIdx.x * 32, k0 = blockIdx.y * 32;
#pragma unroll
  for (int i = 0; i < 32; i += 8)
    tile[ty + i][tx] = W[(size_t)(k0 + ty + i) * N + n0 + tx];
  __syncthreads();
#pragma unroll
  for (int i = 0; i < 32; i += 8) {
    float val = tile[tx][ty + i];
    f16_t hi = (f16_t)val;
    f16_t lo = (f16_t)(val - (float)hi);
    size_t idx = (size_t)(n0 + ty + i) * K + k0 + tx;
    WtH[idx] = hi;
    WtL[idx] = lo;
  }
}

// Zero Bt pad rows [3168, 3200) for both hi/lo.
__global__ void zeropad_bt_k(f16_t* __restrict__ BtH, f16_t* __restrict__ BtL) {
  int i = blockIdx.x * 256 + threadIdx.x;   // 128 x 256 = 32768 = 32 rows
  size_t base = (size_t)(3 * WFP) * DD + i;
  BtH[base] = (f16_t)0.f;
  BtL[base] = (f16_t)0.f;
}

// ---------------------------------------------------------------------------
// LayerNorm (fp32 in) -> split fp16 hi/lo.  One block per row of 1024.
// ---------------------------------------------------------------------------
__global__ __launch_bounds__(256) void ln_cast2_k(
    const float* __restrict__ x, const float* __restrict__ g,
    const float* __restrict__ b, f16_t* __restrict__ hH,
    f16_t* __restrict__ hL) {
  const int row = blockIdx.x, tid = threadIdx.x;
  __shared__ float red[8];
  const float* xr = x + (size_t)row * DD;
  float v[4], ls = 0.f, lq = 0.f;
#pragma unroll
  for (int i = 0; i < 4; ++i) {
    v[i] = xr[i * 256 + tid];
    ls += v[i];
    lq += v[i] * v[i];
  }
#pragma unroll
  for (int o = 32; o > 0; o >>= 1) {
    ls += __shfl_down(ls, o);
    lq += __shfl_down(lq, o);
  }
  const int lane = tid & 63, w = tid >> 6;
  if (lane == 0) { red[w] = ls; red[w + 4] = lq; }
  __syncthreads();
  const float S = red[0] + red[1] + red[2] + red[3];
  const float Q = red[4] + red[5] + red[6] + red[7];
  const float mean = S * (1.f / 1024.f);
  const float var = Q * (1.f / 1024.f) - mean * mean;
  const float rs = rsqrtf(var + 1e-5f);
#pragma unroll
  for (int i = 0; i < 4; ++i) {
    int n = i * 256 + tid;
    float val = (v[i] - mean) * rs * g[n] + b[n];
    f16_t hi = (f16_t)val;
    hH[(size_t)row * DD + n] = hi;
    hL[(size_t)row * DD + n] = (f16_t)(val - (float)hi);
  }
}

// ---------------------------------------------------------------------------
// Split-fp16 GEMM with XCD-band swizzle.  Grid must be 1-D, M/128 * N/128
// blocks, divisible by 8.  rank = (lin&7)*per + (lin>>3) gives each XCD a
// contiguous band of (n,m) pairs -> few N-tiles per XCD -> B resident in
// that XCD's 4 MB L2 (round-2's accidental win, now by construction).
// ---------------------------------------------------------------------------
__global__ __launch_bounds__(256, 2) void gemm_split_k(
    const f16_t* __restrict__ Ahi, const f16_t* __restrict__ Alo,
    const f16_t* __restrict__ Bhi, const f16_t* __restrict__ Blo,
    const float* __restrict__ bias, float* __restrict__ outF,
    int M, int N, int K) {
  __shared__ alignas(16) f16_t AsH[128 * 40];
  __shared__ alignas(16) f16_t AsL[128 * 40];
  __shared__ alignas(16) f16_t BsH[128 * 40];
  __shared__ alignas(16) f16_t BsL[128 * 40];
  const int tid = threadIdx.x;
  const int lane = tid & 63;
  const int w = tid >> 6;
  const int wm = w >> 1, wn = w & 1;

  const int ntm = M >> 7;
  const int total = (N >> 7) * ntm;
  const int per = total >> 3;           // blocks per XCD (total % 8 == 0)
  const int lin = blockIdx.x;
  const int rank = (lin & 7) * per + (lin >> 3);
  const int bn = (rank / ntm) * 128;
  const int bm = (rank % ntm) * 128;

  f32x4 acc[4][4];
#pragma unroll
  for (int i = 0; i < 4; ++i)
#pragma unroll
    for (int j = 0; j < 4; ++j) acc[i][j] = (f32x4){0.f, 0.f, 0.f, 0.f};

  for (int kt = 0; kt < K; kt += 32) {
#pragma unroll
    for (int i = 0; i < 2; ++i) {
      int c = i * 256 + tid;      // 0..511 chunks of 16B (128 rows x 4 groups)
      int row = c >> 2;
      int g = c & 3;
      size_t ga = (size_t)(bm + row) * K + kt + g * 8;
      *(uint4*)(&AsH[row * 40 + g * 8]) = *(const uint4*)(Ahi + ga);
      *(uint4*)(&AsL[row * 40 + g * 8]) = *(const uint4*)(Alo + ga);
      size_t gb = (size_t)(bn + row) * K + kt + g * 8;
      *(uint4*)(&BsH[row * 40 + g * 8]) = *(const uint4*)(Bhi + gb);
      *(uint4*)(&BsL[row * 40 + g * 8]) = *(const uint4*)(Blo + gb);
    }
    __syncthreads();
    {
      const int col = (lane >> 4) * 8;
      f16x8 ah[4], al[4], bh[4], bl[4];
#pragma unroll
      for (int mt = 0; mt < 4; ++mt) {
        int m = wm * 64 + mt * 16 + (lane & 15);
        ah[mt] = *(const f16x8*)(&AsH[m * 40 + col]);
        al[mt] = *(const f16x8*)(&AsL[m * 40 + col]);
      }
#pragma unroll
      for (int nt = 0; nt < 4; ++nt) {
        int n = wn * 64 + nt * 16 + (lane & 15);
        bh[nt] = *(const f16x8*)(&BsH[n * 40 + col]);
        bl[nt] = *(const f16x8*)(&BsL[n * 40 + col]);
      }
#pragma unroll
      for (int mt = 0; mt < 4; ++mt)
#pragma unroll
        for (int nt = 0; nt < 4; ++nt) {
          acc[mt][nt] = __builtin_amdgcn_mfma_f32_16x16x32_f16(
              ah[mt], bh[nt], acc[mt][nt], 0, 0, 0);
          acc[mt][nt] = __builtin_amdgcn_mfma_f32_16x16x32_f16(
              al[mt], bh[nt], acc[mt][nt], 0, 0, 0);
          acc[mt][nt] = __builtin_amdgcn_mfma_f32_16x16x32_f16(
              ah[mt], bl[nt], acc[mt][nt], 0, 0, 0);
        }
    }
    __syncthreads();
  }

  const int q = lane >> 4;
  const int cn = lane & 15;
#pragma unroll
  for (int mt = 0; mt < 4; ++mt) {
#pragma unroll
    for (int nt = 0; nt < 4; ++nt) {
      const int gcol = bn + wn * 64 + nt * 16 + cn;
      const float bv = bias[gcol];
      const int grow0 = bm + wm * 64 + mt * 16 + q * 4;
#pragma unroll
      for (int i = 0; i < 4; ++i) {
        size_t idx = (size_t)(grow0 + i) * N + gcol;
        outF[idx] = acc[mt][nt][i] + bv;
      }
    }
  }
}

// ---------------------------------------------------------------------------
// Plain fp16 GEMM: C(M,N) = A(M,K) @ Bt(N,K)^T + bias.
// EPI 1: gelu(exact) -> fp16.  EPI 2: +resid -> fp32.
// grid.x (N-tiles) is 32 or 8 here: both %8==0 -> XCD = n%8 naturally.
// ---------------------------------------------------------------------------
template <int EPI>
__global__ __launch_bounds__(256, 2) void gemm_bt_k(
    const f16_t* __restrict__ A, const f16_t* __restrict__ Bt,
    const float* __restrict__ bias, const float* __restrict__ resid,
    float* __restrict__ outF, f16_t* __restrict__ outH, int M, int N, int K) {
  __shared__ alignas(16) f16_t As[128 * 72];
  __shared__ alignas(16) f16_t Bs[128 * 72];
  const int tid = threadIdx.x;
  const int lane = tid & 63;
  const int w = tid >> 6;
  const int wm = w >> 1, wn = w & 1;
  const int bm = blockIdx.y * 128;
  const int bn = blockIdx.x * 128;

  f32x4 acc[4][4];
#pragma unroll
  for (int i = 0; i < 4; ++i)
#pragma unroll
    for (int j = 0; j < 4; ++j) acc[i][j] = (f32x4){0.f, 0.f, 0.f, 0.f};

  for (int kt = 0; kt < K; kt += 64) {
#pragma unroll
    for (int i = 0; i < 4; ++i) {
      int c = i * 256 + tid;
      int row = c >> 3;
      int g = c & 7;
      const f16_t* ga = A + (size_t)(bm + row) * K + kt + g * 8;
      *(uint4*)(&As[row * 72 + g * 8]) = *(const uint4*)ga;
      const f16_t* gb = Bt + (size_t)(bn + row) * K + kt + g * 8;
      *(uint4*)(&Bs[row * 72 + g * 8]) = *(const uint4*)gb;
    }
    __syncthreads();
#pragma unroll
    for (int ks = 0; ks < 2; ++ks) {
      f16x8 af[4], bfv[4];
      const int col = ks * 32 + (lane >> 4) * 8;
#pragma unroll
      for (int mt = 0; mt < 4; ++mt) {
        int m = wm * 64 + mt * 16 + (lane & 15);
        af[mt] = *(const f16x8*)(&As[m * 72 + col]);
      }
#pragma unroll
      for (int nt = 0; nt < 4; ++nt) {
        int n = wn * 64 + nt * 16 + (lane & 15);
        bfv[nt] = *(const f16x8*)(&Bs[n * 72 + col]);
      }
#pragma unroll
      for (int mt = 0; mt < 4; ++mt)
#pragma unroll
        for (int nt = 0; nt < 4; ++nt)
          acc[mt][nt] = __builtin_amdgcn_mfma_f32_16x16x32_f16(
              af[mt], bfv[nt], acc[mt][nt], 0, 0, 0);
    }
    __syncthreads();
  }

  const int q = lane >> 4;
  const int cn = lane & 15;
#pragma unroll
  for (int mt = 0; mt < 4; ++mt) {
#pragma unroll
    for (int nt = 0; nt < 4; ++nt) {
      const int gcol = bn + wn * 64 + nt * 16 + cn;
      const float bv = bias[gcol];
      const int grow0 = bm + wm * 64 + mt * 16 + q * 4;
#pragma unroll
      for (int i = 0; i < 4; ++i) {
        float val = acc[mt][nt][i] + bv;
        size_t idx = (size_t)(grow0 + i) * N + gcol;
        if (EPI == 1) {
          float ge = 0.5f * val * (1.0f + erff(val * 0.70710678118654752f));
          outH[idx] = (f16_t)ge;
        } else {
          outF[idx] = val + resid[idx];
        }
      }
    }
  }
}

// ---------------------------------------------------------------------------
// Inline normalize helpers reading raw bins from qkv_f rows (1600 float2).
// q at [f], k at [528+f], v at [1056+f].
// ---------------------------------------------------------------------------
__device__ __forceinline__ float2 unitc(float2 a) {
  float inv = 1.0f / fmaxf(sqrtf(a.x * a.x + a.y * a.y), 1e-8f);
  return make_float2(a.x * inv, a.y * inv);
}
__device__ __forceinline__ float2 bind_bin(const float2* r, int f) {
  float2 kn = unitc(r[528 + f]);
  float2 vn = unitc(r[1056 + f]);
  return cmul(kn, vn);
}

// ---------------------------------------------------------------------------
// 3-pass parallel prefix sum over S per (batch, bin), P computed inline.
// Pass 1: chunk totals.  Pass 2: exclusive scan of totals.
// Pass 3: recompute P, add chunk prefix, write Scum.
// ---------------------------------------------------------------------------
__global__ __launch_bounds__(256) void scan_pass1_k(
    const float* __restrict__ qkvF, float2* __restrict__ T) {
  const int b = blockIdx.x >> 6, sc = blockIdx.x & 63;
  const int s0 = sc * SCHUNK;
  const float2* base = (const float2*)(qkvF + ((size_t)(b * SSEQ + s0)) * NQKV);
  for (int f = threadIdx.x; f < FBINS; f += 256) {
    float2 acc = make_float2(0.f, 0.f);
    const float2* r = base;
    for (int i = 0; i < SCHUNK; ++i) {
      float2 pv = bind_bin(r, f);
      acc.x += pv.x; acc.y += pv.y;
      r += NQKV / 2;
    }
    T[((size_t)b * NCHUNK + sc) * FBINS + f] = acc;
  }
}

__global__ void scan_pass2_k(float2* __restrict__ T) {
  const int idx = blockIdx.x * 256 + threadIdx.x;
  if (idx >= NB * FBINS) return;
  const int b = idx / FBINS, f = idx % FBINS;
  float2 acc = make_float2(0.f, 0.f);
  for (int sc = 0; sc < NCHUNK; ++sc) {
    size_t a = ((size_t)b * NCHUNK + sc) * FBINS + f;
    float2 v = T[a];
    T[a] = acc;
    acc.x += v.x; acc.y += v.y;
  }
}

__global__ __launch_bounds__(256) void scan_pass3_k(
    const float* __restrict__ qkvF, const float2* __restrict__ T,
    float2* __restrict__ Scum) {
  const int b = blockIdx.x >> 6, sc = blockIdx.x & 63;
  const int s0 = sc * SCHUNK;
  const float2* base = (const float2*)(qkvF + ((size_t)(b * SSEQ + s0)) * NQKV);
  for (int f = threadIdx.x; f < FBINS; f += 256) {
    float2 acc = T[((size_t)b * NCHUNK + sc) * FBINS + f];
    const float2* r = base;
    size_t orow = ((size_t)(b * SSEQ + s0)) * FPAD + f;
    for (int i = 0; i < SCHUNK; ++i) {
      float2 pv = bind_bin(r, f);
      acc.x += pv.x; acc.y += pv.y;
      Scum[orow] = acc;
      r += NQKV / 2;
      orow += FPAD;
    }
  }
}

// ---------------------------------------------------------------------------
// Per-row: Fq = unit(q bins); M = Scum .* conj(Fq); mixed = irfft(M);
// x2 = x + mixed; h2 = LN2(x2) -> fp16.
// ---------------------------------------------------------------------------
__global__ __launch_bounds__(256) void unbind_ln2_k(
    const float2* __restrict__ Scum, const float* __restrict__ qkvF,
    const float* __restrict__ x, float* __restrict__ x2out,
    f16_t* __restrict__ h2, const float* __restrict__ g2,
    const float* __restrict__ b2) {
  __shared__ float2 tw[512];
  __shared__ float2 bufA[1024];
  __shared__ float2 bufB[1024];
  __shared__ float red[8];
  const int tid = threadIdx.x;
  const int row = blockIdx.x;

  for (int t = tid; t < 512; t += 256) {
    float ang = 6.2831853071795864769f * (float)t * (1.0f / 1024.0f);
    tw[t] = make_float2(cosf(ang), sinf(ang));  // inverse twiddles
  }
  const float2* qrow = (const float2*)(qkvF + (size_t)row * NQKV);
  for (int t = tid; t <= 512; t += 256) {
    float2 sc = Scum[(size_t)row * FPAD + t];
    float2 fq = unitc(qrow[t]);
    float2 Mv = make_float2(sc.x * fq.x + sc.y * fq.y, sc.y * fq.x - sc.x * fq.y);
    bufA[t] = Mv;
    if (t >= 1 && t < 512) bufA[1024 - t] = make_float2(Mv.x, -Mv.y);
  }
  __syncthreads();
  fft1024(bufA, bufB, tw, tid);

  const float* xr = x + (size_t)row * DD;
  float v[4], ls = 0.f, lq = 0.f;
#pragma unroll
  for (int i = 0; i < 4; ++i) {
    int n = i * 256 + tid;
    float val = xr[n] + bufA[n].x * (1.0f / 1024.0f);
    x2out[(size_t)row * DD + n] = val;
    v[i] = val;
    ls += val;
    lq += val * val;
  }
#pragma unroll
  for (int o = 32; o > 0; o >>= 1) {
    ls += __shfl_down(ls, o);
    lq += __shfl_down(lq, o);
  }
  const int lane = tid & 63, w = tid >> 6;
  if (lane == 0) { red[w] = ls; red[w + 4] = lq; }
  __syncthreads();
  const float S = red[0] + red[1] + red[2] + red[3];
  const float Q = red[4] + red[5] + red[6] + red[7];
  const float mean = S * (1.f / 1024.f);
  const float var = Q * (1.f / 1024.f) - mean * mean;
  const float rs = rsqrtf(var + 1e-5f);
  f16_t* hr = h2 + (size_t)row * DD;
#pragma unroll
  for (int i = 0; i < 4; ++i) {
    int n = i * 256 + tid;
    hr[n] = (f16_t)((v[i] - mean) * rs * g2[n] + b2[n]);
  }
}

// ---------------------------------------------------------------------------
extern "C" void kernel_launch(void* const* d_in, const int* in_sizes, int n_in,
                              void* d_out, int out_size, void* d_ws,
                              size_t ws_size, hipStream_t stream) {
  const float* x     = (const float*)d_in[0];
  const float* Wq    = (const float*)d_in[1];
  const float* bq    = (const float*)d_in[2];
  const float* Wk    = (const float*)d_in[3];
  const float* bk    = (const float*)d_in[4];
  const float* Wv    = (const float*)d_in[5];
  const float* bv    = (const float*)d_in[6];
  const float* ln1_g = (const float*)d_in[7];
  const float* ln1_b = (const float*)d_in[8];
  const float* ln2_g = (const float*)d_in[9];
  const float* ln2_b = (const float*)d_in[10];
  const float* W1    = (const float*)d_in[11];
  const float* b1    = (const float*)d_in[12];
  const float* W2    = (const float*)d_in[13];
  const float* b2    = (const float*)d_in[14];
  float* out = (float*)d_out;

  char* p = (char*)d_ws;
  auto take = [&](size_t bytes) {
    char* r = p;
    p += (bytes + 255) & ~(size_t)255;
    return r;
  };
  f16_t* BtH   = (f16_t*)take((size_t)NQKV * DD * sizeof(f16_t));
  f16_t* BtL   = (f16_t*)take((size_t)NQKV * DD * sizeof(f16_t));
  f16_t* W1T   = (f16_t*)take((size_t)NHID * DD * sizeof(f16_t));
  f16_t* W2T   = (f16_t*)take((size_t)DD * NHID * sizeof(f16_t));
  float* biasC = (float*)take((size_t)NQKV * sizeof(float));
  f16_t* hbuf  = (f16_t*)take((size_t)MROWS * DD * sizeof(f16_t));   // h_hi, then h2
  char*  big   = take((size_t)MROWS * NQKV * sizeof(float));         // WfAll, qkvF, mlp1
  float2* Scum = (float2*)take((size_t)MROWS * FPAD * sizeof(float2));
  float* x2    = (float*)take((size_t)MROWS * DD * sizeof(float));
  float2* Tch  = (float2*)take((size_t)NB * NCHUNK * FBINS * sizeof(float2));
  // time-disjoint aliases:
  float* WfAll   = (float*)big;   // consumed by transposes before gemm writes qkvF
  float* qkv_f   = (float*)big;   // bins from split GEMM (alive through unbind)
  f16_t* mlp1    = (f16_t*)big;   // gelu output, after qkv_f dead
  f16_t* hlo     = (f16_t*)x2;    // LN1 lo; dead before unbind writes x2

  // 1. FFT weight rows (fp32) -> WfAll[p][k][1056]
  wfft_k<<<3 * DD, 256, 0, stream>>>(Wq, Wk, Wv, WfAll);
  // 2. transpose + hi/lo split -> Bt (3*1056 x 1024), then zero pad rows
  for (int pp = 0; pp < 3; ++pp)
    transpose_cast2_k<<<dim3(WFP / 32, DD / 32), 256, 0, stream>>>(
        WfAll + (size_t)pp * DD * WFP,
        BtH + (size_t)pp * WFP * DD,
        BtL + (size_t)pp * WFP * DD, DD, WFP);
  zeropad_bt_k<<<128, 256, 0, stream>>>(BtH, BtL);
  // 3. FFT biases -> biasC
  bfft_k<<<4, 256, 0, stream>>>(bq, bk, bv, biasC);
  // 4. MLP weights -> transposed fp16
  transpose_cast_k<<<dim3(128, 32), 256, 0, stream>>>(W1, W1T, DD, NHID);
  transpose_cast_k<<<dim3(32, 128), 256, 0, stream>>>(W2, W2T, NHID, DD);

  // 5. h = LN1(x) -> hi/lo fp16 pair
  ln_cast2_k<<<MROWS, 256, 0, stream>>>(x, ln1_g, ln1_b, hbuf, hlo);

  // 6. Fourier bins directly: qkv_f = h @ rfft_rows(W)^T + rfft(bias)
  //    1-D grid, XCD-band swizzled inside the kernel.
  gemm_split_k<<<(NQKV / 128) * (MROWS / 128), 256, 0, stream>>>(
      hbuf, hlo, BtH, BtL, biasC, qkv_f, MROWS, NQKV, DD);

  // 7. causal prefix sum over S (P = unit(Fk).*unit(Fv) computed inline)
  scan_pass1_k<<<NB * NCHUNK, 256, 0, stream>>>(qkv_f, Tch);
  scan_pass2_k<<<(NB * FBINS + 255) / 256, 256, 0, stream>>>(Tch);
  scan_pass3_k<<<NB * NCHUNK, 256, 0, stream>>>(qkv_f, Tch, Scum);

  // 8. unbind (Fq normalized inline) + residual + LN2
  unbind_ln2_k<<<MROWS, 256, 0, stream>>>(Scum, qkv_f, x, x2, hbuf, ln2_g, ln2_b);

  // 9. mlp1 = gelu(h2 @ W1 + b1)   (qkv_f dead -> reuse big as mlp1)
  gemm_bt_k<1><<<dim3(NHID / 128, MROWS / 128), 256, 0, stream>>>(
      hbuf, W1T, b1, nullptr, nullptr, mlp1, MROWS, NHID, DD);

  // 10. out = x2 + mlp1 @ W2 + b2
  gemm_bt_k<2><<<dim3(DD / 128, MROWS / 128), 256, 0, stream>>>(
      mlp1, W2T, b2, x2, out, nullptr, MROWS, DD, NHID);
}

// Round 5
// 663.334 us; speedup vs baseline: 1.2463x; 1.0660x over previous
//
#include <hip/hip_runtime.h>
#include <cstdint>
#include <cstddef>

// Problem constants (B=4, S=2048, D=1024)
#define DD 1024
#define SSEQ 2048
#define NB 4
#define MROWS 8192          // B*S
#define FBINS 513           // rfft bins for N=1024
#define FPAD 520            // padded row stride for Scum buffer
#define NQKV 3200           // 3 * 1056 (padded complex cols) rounded to 25*128
#define WFP 1056            // per-projection padded complex column count
#define NHID 4096
#define NCHUNK 64           // scan chunks over S
#define SCHUNK 32           // S per chunk

typedef _Float16 f16_t;
typedef _Float16 f16x8 __attribute__((ext_vector_type(8)));
typedef float f32x4 __attribute__((ext_vector_type(4)));

__device__ __forceinline__ float2 cmul(float2 a, float2 b) {
  return make_float2(a.x * b.x - a.y * b.y, a.x * b.y + a.y * b.x);
}

// Async global->LDS 16B copy (m97: width=16 emits global_load_lds_dwordx4).
// HW deposits lane i's 16B at (wave-uniform lds base) + i*16.
__device__ __forceinline__ void async_cp16(const void* g, void* l) {
  __builtin_amdgcn_global_load_lds(
      (const __attribute__((address_space(1))) void*)g,
      (__attribute__((address_space(3))) void*)l, 16, 0, 0);
}

// 1024-pt complex FFT over LDS ping-pong buffers; result lands back in bufA.
__device__ __forceinline__ void fft1024(float2* bufA, float2* bufB,
                                        const float2* tw, int tid) {
  float2* s = bufA;
  float2* d = bufB;
  for (int m = 1; m < 1024; m <<= 1) {
#pragma unroll
    for (int r2 = 0; r2 < 2; ++r2) {
      int u = tid + r2 * 256;
      int k = u & (m - 1);
      int jm = u - k;
      float2 c0 = s[u];
      float2 c1 = s[u + 512];
      float2 wt = tw[jm];
      float2 su = make_float2(c0.x + c1.x, c0.y + c1.y);
      float2 df = make_float2(c0.x - c1.x, c0.y - c1.y);
      float2 pr = cmul(wt, df);
      d[2 * jm + k] = su;
      d[2 * jm + k + m] = pr;
    }
    __syncthreads();
    float2* tmp = s; s = d; d = tmp;
  }
}

// ---------------------------------------------------------------------------
// Weight-row FFT: WfAll[p][k][j] = interleaved Re/Im of rfft(W_p[k, :]).
// ---------------------------------------------------------------------------
__global__ __launch_bounds__(256) void wfft_k(
    const float* __restrict__ Wq, const float* __restrict__ Wk,
    const float* __restrict__ Wv, float* __restrict__ WfAll) {
  __shared__ float2 tw[512];
  __shared__ float2 bufA[1024];
  __shared__ float2 bufB[1024];
  const int tid = threadIdx.x;
  const int p = blockIdx.x >> 10, k = blockIdx.x & 1023;
  const float* W = (p == 0) ? Wq : ((p == 1) ? Wk : Wv);
  for (int t = tid; t < 512; t += 256) {
    float ang = -6.2831853071795864769f * (float)t * (1.0f / 1024.0f);
    tw[t] = make_float2(cosf(ang), sinf(ang));
  }
  const float* src = W + (size_t)k * DD;
  for (int t = tid; t < 1024; t += 256) bufA[t] = make_float2(src[t], 0.f);
  __syncthreads();
  fft1024(bufA, bufB, tw, tid);
  float* dst = WfAll + ((size_t)p * DD + k) * WFP;
  for (int t = tid; t <= 512; t += 256) {
    float2 f = bufA[t];
    dst[2 * t] = f.x;
    dst[2 * t + 1] = f.y;
  }
  for (int j = 1026 + tid; j < WFP; j += 256) dst[j] = 0.f;
}

// ---------------------------------------------------------------------------
// Bias FFT (blocks 0..2) + pad-zero block 3.
// ---------------------------------------------------------------------------
__global__ __launch_bounds__(256) void bfft_k(
    const float* __restrict__ bq, const float* __restrict__ bk,
    const float* __restrict__ bv, float* __restrict__ biasC) {
  __shared__ float2 tw[512];
  __shared__ float2 bufA[1024];
  __shared__ float2 bufB[1024];
  const int tid = threadIdx.x;
  const int p = blockIdx.x;
  if (p == 3) {
    for (int j = 3 * WFP + tid; j < NQKV; j += 256) biasC[j] = 0.f;
    return;
  }
  const float* bsrc = (p == 0) ? bq : ((p == 1) ? bk : bv);
  for (int t = tid; t < 512; t += 256) {
    float ang = -6.2831853071795864769f * (float)t * (1.0f / 1024.0f);
    tw[t] = make_float2(cosf(ang), sinf(ang));
  }
  for (int t = tid; t < 1024; t += 256) bufA[t] = make_float2(bsrc[t], 0.f);
  __syncthreads();
  fft1024(bufA, bufB, tw, tid);
  float* dst = biasC + (size_t)p * WFP;
  for (int t = tid; t <= 512; t += 256) {
    float2 f = bufA[t];
    dst[2 * t] = f.x;
    dst[2 * t + 1] = f.y;
  }
  for (int j = 1026 + tid; j < WFP; j += 256) dst[j] = 0.f;
}

// ---------------------------------------------------------------------------
// Transpose + cast fp32 (K x N) -> fp16 (N x K)
// ---------------------------------------------------------------------------
__global__ __launch_bounds__(256) void transpose_cast_k(
    const float* __restrict__ W, f16_t* __restrict__ Wt, int K, int N) {
  __shared__ float tile[32][33];
  const int tx = threadIdx.x & 31, ty = threadIdx.x >> 5;  // 32 x 8
  const int n0 = blockIdx.x * 32, k0 = blockIdx.y * 32;
#pragma unroll
  for (int i = 0; i < 32; i += 8)
    tile[ty + i][tx] = W[(size_t)(k0 + ty + i) * N + n0 + tx];
  __syncthreads();
#pragma unroll
  for (int i = 0; i < 32; i += 8)
    Wt[(size_t)(n0 + ty + i) * K + k0 + tx] = (f16_t)tile[tx][ty + i];
}

// Transpose + split-cast fp32 (K x N) -> fp16 hi/lo pair (N x K)
__global__ __launch_bounds__(256) void transpose_cast2_k(
    const float* __restrict__ W, f16_t* __restrict__ WtH,
    f16_t* __restrict__ WtL, int K, int N) {
  __shared__ float tile[32][33];
  const int tx = threadIdx.x & 31, ty = threadIdx.x >> 5;  // 32 x 8
  const int n0 = blockIdx.x * 32, k0 = blockIdx.y * 32;
#pragma unroll
  for (int i = 0; i < 32; i += 8)
    tile[ty + i][tx] = W[(size_t)(k0 + ty + i) * N + n0 + tx];
  __syncthreads();
#pragma unroll
  for (int i = 0; i < 32; i += 8) {
    float val = tile[tx][ty + i];
    f16_t hi = (f16_t)val;
    f16_t lo = (f16_t)(val - (float)hi);
    size_t idx = (size_t)(n0 + ty + i) * K + k0 + tx;
    WtH[idx] = hi;
    WtL[idx] = lo;
  }
}

// Zero Bt pad rows [3168, 3200) for both hi/lo.
__global__ void zeropad_bt_k(f16_t* __restrict__ BtH, f16_t* __restrict__ BtL) {
  int i = blockIdx.x * 256 + threadIdx.x;   // 128 x 256 = 32768 = 32 rows
  size_t base = (size_t)(3 * WFP) * DD + i;
  BtH[base] = (f16_t)0.f;
  BtL[base] = (f16_t)0.f;
}

// ---------------------------------------------------------------------------
// LayerNorm (fp32 in) -> split fp16 hi/lo.  One block per row of 1024.
// ---------------------------------------------------------------------------
__global__ __launch_bounds__(256) void ln_cast2_k(
    const float* __restrict__ x, const float* __restrict__ g,
    const float* __restrict__ b, f16_t* __restrict__ hH,
    f16_t* __restrict__ hL) {
  const int row = blockIdx.x, tid = threadIdx.x;
  __shared__ float red[8];
  const float* xr = x + (size_t)row * DD;
  float v[4], ls = 0.f, lq = 0.f;
#pragma unroll
  for (int i = 0; i < 4; ++i) {
    v[i] = xr[i * 256 + tid];
    ls += v[i];
    lq += v[i] * v[i];
  }
#pragma unroll
  for (int o = 32; o > 0; o >>= 1) {
    ls += __shfl_down(ls, o);
    lq += __shfl_down(lq, o);
  }
  const int lane = tid & 63, w = tid >> 6;
  if (lane == 0) { red[w] = ls; red[w + 4] = lq; }
  __syncthreads();
  const float S = red[0] + red[1] + red[2] + red[3];
  const float Q = red[4] + red[5] + red[6] + red[7];
  const float mean = S * (1.f / 1024.f);
  const float var = Q * (1.f / 1024.f) - mean * mean;
  const float rs = rsqrtf(var + 1e-5f);
#pragma unroll
  for (int i = 0; i < 4; ++i) {
    int n = i * 256 + tid;
    float val = (v[i] - mean) * rs * g[n] + b[n];
    f16_t hi = (f16_t)val;
    hH[(size_t)row * DD + n] = hi;
    hL[(size_t)row * DD + n] = (f16_t)(val - (float)hi);
  }
}

// ---------------------------------------------------------------------------
// Split-fp16 GEMM, async global->LDS staging, XCD-band swizzle.
// BK=32; LDS tiles unpadded 128x32 f16 (64B rows, 4 16B-slots/row).
// Slot swizzle: slot s of row r holds global group (s - ((r>>1)&3)) & 3
// -> ds_read_b128 spreads evenly over all bank-quads (conflict floor).
// ---------------------------------------------------------------------------
__global__ __launch_bounds__(256, 2) void gemm_split_k(
    const f16_t* __restrict__ Ahi, const f16_t* __restrict__ Alo,
    const f16_t* __restrict__ Bhi, const f16_t* __restrict__ Blo,
    const float* __restrict__ bias, float* __restrict__ outF,
    int M, int N, int K) {
  __shared__ alignas(16) f16_t AsH[128 * 32];
  __shared__ alignas(16) f16_t AsL[128 * 32];
  __shared__ alignas(16) f16_t BsH[128 * 32];
  __shared__ alignas(16) f16_t BsL[128 * 32];
  const int tid = threadIdx.x;
  const int lane = tid & 63;
  const int w = tid >> 6;
  const int wm = w >> 1, wn = w & 1;

  const int ntm = M >> 7;
  const int total = (N >> 7) * ntm;
  const int per = total >> 3;           // blocks per XCD (total % 8 == 0)
  const int lin = blockIdx.x;
  const int rank = (lin & 7) * per + (lin >> 3);
  const int bn = (rank / ntm) * 128;
  const int bm = (rank % ntm) * 128;

  f32x4 acc[4][4];
#pragma unroll
  for (int i = 0; i < 4; ++i)
#pragma unroll
    for (int j = 0; j < 4; ++j) acc[i][j] = (f32x4){0.f, 0.f, 0.f, 0.f};

  // staging geometry: wave-chunk = 1KB = 16 rows x 64B; 2 iters x 4 waves
  const int srow = lane >> 2;           // 0..15 within chunk
  const int slot = lane & 3;

  for (int kt = 0; kt < K; kt += 32) {
#pragma unroll
    for (int i = 0; i < 2; ++i) {
      const int rb = (i * 4 + w) * 16;
      const int row = rb + srow;
      const int gg = (slot - ((row >> 1) & 3)) & 3;  // swizzled source group
      size_t ga = (size_t)(bm + row) * K + kt + gg * 8;
      size_t gb = (size_t)(bn + row) * K + kt + gg * 8;
      async_cp16(Ahi + ga, &AsH[rb * 32]);
      async_cp16(Alo + ga, &AsL[rb * 32]);
      async_cp16(Bhi + gb, &BsH[rb * 32]);
      async_cp16(Blo + gb, &BsL[rb * 32]);
    }
    __syncthreads();
    {
      const int cg = lane >> 4;         // wanted 16B group (col = cg*8 f16)
      f16x8 ah[4], al[4], bh[4], bl[4];
#pragma unroll
      for (int mt = 0; mt < 4; ++mt) {
        int m = wm * 64 + mt * 16 + (lane & 15);
        int sl = (cg + ((m >> 1) & 3)) & 3;
        ah[mt] = *(const f16x8*)(&AsH[m * 32 + sl * 8]);
        al[mt] = *(const f16x8*)(&AsL[m * 32 + sl * 8]);
      }
#pragma unroll
      for (int nt = 0; nt < 4; ++nt) {
        int n = wn * 64 + nt * 16 + (lane & 15);
        int sl = (cg + ((n >> 1) & 3)) & 3;
        bh[nt] = *(const f16x8*)(&BsH[n * 32 + sl * 8]);
        bl[nt] = *(const f16x8*)(&BsL[n * 32 + sl * 8]);
      }
#pragma unroll
      for (int mt = 0; mt < 4; ++mt)
#pragma unroll
        for (int nt = 0; nt < 4; ++nt) {
          acc[mt][nt] = __builtin_amdgcn_mfma_f32_16x16x32_f16(
              ah[mt], bh[nt], acc[mt][nt], 0, 0, 0);
          acc[mt][nt] = __builtin_amdgcn_mfma_f32_16x16x32_f16(
              al[mt], bh[nt], acc[mt][nt], 0, 0, 0);
          acc[mt][nt] = __builtin_amdgcn_mfma_f32_16x16x32_f16(
              ah[mt], bl[nt], acc[mt][nt], 0, 0, 0);
        }
    }
    __syncthreads();
  }

  const int q = lane >> 4;
  const int cn = lane & 15;
#pragma unroll
  for (int mt = 0; mt < 4; ++mt) {
#pragma unroll
    for (int nt = 0; nt < 4; ++nt) {
      const int gcol = bn + wn * 64 + nt * 16 + cn;
      const float bv = bias[gcol];
      const int grow0 = bm + wm * 64 + mt * 16 + q * 4;
#pragma unroll
      for (int i = 0; i < 4; ++i) {
        size_t idx = (size_t)(grow0 + i) * N + gcol;
        outF[idx] = acc[mt][nt][i] + bv;
      }
    }
  }
}

// ---------------------------------------------------------------------------
// Plain fp16 GEMM, async global->LDS staging.
// BK=64; LDS tiles unpadded 128x64 f16 (128B rows, 8 16B-slots/row).
// Slot swizzle: slot s of row r holds global group (s - (r&7)) & 7.
// EPI 1: gelu(exact) -> fp16.  EPI 2: +resid -> fp32.
// ---------------------------------------------------------------------------
template <int EPI>
__global__ __launch_bounds__(256, 2) void gemm_bt_k(
    const f16_t* __restrict__ A, const f16_t* __restrict__ Bt,
    const float* __restrict__ bias, const float* __restrict__ resid,
    float* __restrict__ outF, f16_t* __restrict__ outH, int M, int N, int K) {
  __shared__ alignas(16) f16_t As[128 * 64];
  __shared__ alignas(16) f16_t Bs[128 * 64];
  const int tid = threadIdx.x;
  const int lane = tid & 63;
  const int w = tid >> 6;
  const int wm = w >> 1, wn = w & 1;
  const int bm = blockIdx.y * 128;
  const int bn = blockIdx.x * 128;

  f32x4 acc[4][4];
#pragma unroll
  for (int i = 0; i < 4; ++i)
#pragma unroll
    for (int j = 0; j < 4; ++j) acc[i][j] = (f32x4){0.f, 0.f, 0.f, 0.f};

  // staging geometry: wave-chunk = 1KB = 8 rows x 128B; 4 iters x 4 waves
  const int srow = lane >> 3;           // 0..7 within chunk
  const int slot = lane & 7;

  for (int kt = 0; kt < K; kt += 64) {
#pragma unroll
    for (int i = 0; i < 4; ++i) {
      const int rb = (i * 4 + w) * 8;
      const int row = rb + srow;
      const int gg = (slot - (row & 7)) & 7;
      const f16_t* ga = A + (size_t)(bm + row) * K + kt + gg * 8;
      const f16_t* gb = Bt + (size_t)(bn + row) * K + kt + gg * 8;
      async_cp16(ga, &As[rb * 64]);
      async_cp16(gb, &Bs[rb * 64]);
    }
    __syncthreads();
#pragma unroll
    for (int ks = 0; ks < 2; ++ks) {
      const int cgbase = ks * 4 + (lane >> 4);
      f16x8 af[4], bfv[4];
#pragma unroll
      for (int mt = 0; mt < 4; ++mt) {
        int m = wm * 64 + mt * 16 + (lane & 15);
        int sl = (cgbase + (m & 7)) & 7;
        af[mt] = *(const f16x8*)(&As[m * 64 + sl * 8]);
      }
#pragma unroll
      for (int nt = 0; nt < 4; ++nt) {
        int n = wn * 64 + nt * 16 + (lane & 15);
        int sl = (cgbase + (n & 7)) & 7;
        bfv[nt] = *(const f16x8*)(&Bs[n * 64 + sl * 8]);
      }
#pragma unroll
      for (int mt = 0; mt < 4; ++mt)
#pragma unroll
        for (int nt = 0; nt < 4; ++nt)
          acc[mt][nt] = __builtin_amdgcn_mfma_f32_16x16x32_f16(
              af[mt], bfv[nt], acc[mt][nt], 0, 0, 0);
    }
    __syncthreads();
  }

  const int q = lane >> 4;
  const int cn = lane & 15;
#pragma unroll
  for (int mt = 0; mt < 4; ++mt) {
#pragma unroll
    for (int nt = 0; nt < 4; ++nt) {
      const int gcol = bn + wn * 64 + nt * 16 + cn;
      const float bv = bias[gcol];
      const int grow0 = bm + wm * 64 + mt * 16 + q * 4;
#pragma unroll
      for (int i = 0; i < 4; ++i) {
        float val = acc[mt][nt][i] + bv;
        size_t idx = (size_t)(grow0 + i) * N + gcol;
        if (EPI == 1) {
          float ge = 0.5f * val * (1.0f + erff(val * 0.70710678118654752f));
          outH[idx] = (f16_t)ge;
        } else {
          outF[idx] = val + resid[idx];
        }
      }
    }
  }
}

// ---------------------------------------------------------------------------
// Inline normalize helpers reading raw bins from qkv_f rows (1600 float2).
// q at [f], k at [528+f], v at [1056+f].
// ---------------------------------------------------------------------------
__device__ __forceinline__ float2 unitc(float2 a) {
  float inv = 1.0f / fmaxf(sqrtf(a.x * a.x + a.y * a.y), 1e-8f);
  return make_float2(a.x * inv, a.y * inv);
}
__device__ __forceinline__ float2 bind_bin(const float2* r, int f) {
  float2 kn = unitc(r[528 + f]);
  float2 vn = unitc(r[1056 + f]);
  return cmul(kn, vn);
}

// ---------------------------------------------------------------------------
// 3-pass parallel prefix sum over S per (batch, bin), P computed inline.
// ---------------------------------------------------------------------------
__global__ __launch_bounds__(256) void scan_pass1_k(
    const float* __restrict__ qkvF, float2* __restrict__ T) {
  const int b = blockIdx.x >> 6, sc = blockIdx.x & 63;
  const int s0 = sc * SCHUNK;
  const float2* base = (const float2*)(qkvF + ((size_t)(b * SSEQ + s0)) * NQKV);
  for (int f = threadIdx.x; f < FBINS; f += 256) {
    float2 acc = make_float2(0.f, 0.f);
    const float2* r = base;
    for (int i = 0; i < SCHUNK; ++i) {
      float2 pv = bind_bin(r, f);
      acc.x += pv.x; acc.y += pv.y;
      r += NQKV / 2;
    }
    T[((size_t)b * NCHUNK + sc) * FBINS + f] = acc;
  }
}

__global__ void scan_pass2_k(float2* __restrict__ T) {
  const int idx = blockIdx.x * 256 + threadIdx.x;
  if (idx >= NB * FBINS) return;
  const int b = idx / FBINS, f = idx % FBINS;
  float2 acc = make_float2(0.f, 0.f);
  for (int sc = 0; sc < NCHUNK; ++sc) {
    size_t a = ((size_t)b * NCHUNK + sc) * FBINS + f;
    float2 v = T[a];
    T[a] = acc;
    acc.x += v.x; acc.y += v.y;
  }
}

__global__ __launch_bounds__(256) void scan_pass3_k(
    const float* __restrict__ qkvF, const float2* __restrict__ T,
    float2* __restrict__ Scum) {
  const int b = blockIdx.x >> 6, sc = blockIdx.x & 63;
  const int s0 = sc * SCHUNK;
  const float2* base = (const float2*)(qkvF + ((size_t)(b * SSEQ + s0)) * NQKV);
  for (int f = threadIdx.x; f < FBINS; f += 256) {
    float2 acc = T[((size_t)b * NCHUNK + sc) * FBINS + f];
    const float2* r = base;
    size_t orow = ((size_t)(b * SSEQ + s0)) * FPAD + f;
    for (int i = 0; i < SCHUNK; ++i) {
      float2 pv = bind_bin(r, f);
      acc.x += pv.x; acc.y += pv.y;
      Scum[orow] = acc;
      r += NQKV / 2;
      orow += FPAD;
    }
  }
}

// ---------------------------------------------------------------------------
// Per-row: Fq = unit(q bins); M = Scum .* conj(Fq); mixed = irfft(M);
// x2 = x + mixed; h2 = LN2(x2) -> fp16.
// ---------------------------------------------------------------------------
__global__ __launch_bounds__(256) void unbind_ln2_k(
    const float2* __restrict__ Scum, const float* __restrict__ qkvF,
    const float* __restrict__ x, float* __restrict__ x2out,
    f16_t* __restrict__ h2, const float* __restrict__ g2,
    const float* __restrict__ b2) {
  __shared__ float2 tw[512];
  __shared__ float2 bufA[1024];
  __shared__ float2 bufB[1024];
  __shared__ float red[8];
  const int tid = threadIdx.x;
  const int row = blockIdx.x;

  for (int t = tid; t < 512; t += 256) {
    float ang = 6.2831853071795864769f * (float)t * (1.0f / 1024.0f);
    tw[t] = make_float2(cosf(ang), sinf(ang));  // inverse twiddles
  }
  const float2* qrow = (const float2*)(qkvF + (size_t)row * NQKV);
  for (int t = tid; t <= 512; t += 256) {
    float2 sc = Scum[(size_t)row * FPAD + t];
    float2 fq = unitc(qrow[t]);
    float2 Mv = make_float2(sc.x * fq.x + sc.y * fq.y, sc.y * fq.x - sc.x * fq.y);
    bufA[t] = Mv;
    if (t >= 1 && t < 512) bufA[1024 - t] = make_float2(Mv.x, -Mv.y);
  }
  __syncthreads();
  fft1024(bufA, bufB, tw, tid);

  const float* xr = x + (size_t)row * DD;
  float v[4], ls = 0.f, lq = 0.f;
#pragma unroll
  for (int i = 0; i < 4; ++i) {
    int n = i * 256 + tid;
    float val = xr[n] + bufA[n].x * (1.0f / 1024.0f);
    x2out[(size_t)row * DD + n] = val;
    v[i] = val;
    ls += val;
    lq += val * val;
  }
#pragma unroll
  for (int o = 32; o > 0; o >>= 1) {
    ls += __shfl_down(ls, o);
    lq += __shfl_down(lq, o);
  }
  const int lane = tid & 63, w = tid >> 6;
  if (lane == 0) { red[w] = ls; red[w + 4] = lq; }
  __syncthreads();
  const float S = red[0] + red[1] + red[2] + red[3];
  const float Q = red[4] + red[5] + red[6] + red[7];
  const float mean = S * (1.f / 1024.f);
  const float var = Q * (1.f / 1024.f) - mean * mean;
  const float rs = rsqrtf(var + 1e-5f);
  f16_t* hr = h2 + (size_t)row * DD;
#pragma unroll
  for (int i = 0; i < 4; ++i) {
    int n = i * 256 + tid;
    hr[n] = (f16_t)((v[i] - mean) * rs * g2[n] + b2[n]);
  }
}

// ---------------------------------------------------------------------------
extern "C" void kernel_launch(void* const* d_in, const int* in_sizes, int n_in,
                              void* d_out, int out_size, void* d_ws,
                              size_t ws_size, hipStream_t stream) {
  const float* x     = (const float*)d_in[0];
  const float* Wq    = (const float*)d_in[1];
  const float* bq    = (const float*)d_in[2];
  const float* Wk    = (const float*)d_in[3];
  const float* bk    = (const float*)d_in[4];
  const float* Wv    = (const float*)d_in[5];
  const float* bv    = (const float*)d_in[6];
  const float* ln1_g = (const float*)d_in[7];
  const float* ln1_b = (const float*)d_in[8];
  const float* ln2_g = (const float*)d_in[9];
  const float* ln2_b = (const float*)d_in[10];
  const float* W1    = (const float*)d_in[11];
  const float* b1    = (const float*)d_in[12];
  const float* W2    = (const float*)d_in[13];
  const float* b2    = (const float*)d_in[14];
  float* out = (float*)d_out;

  char* p = (char*)d_ws;
  auto take = [&](size_t bytes) {
    char* r = p;
    p += (bytes + 255) & ~(size_t)255;
    return r;
  };
  f16_t* BtH   = (f16_t*)take((size_t)NQKV * DD * sizeof(f16_t));
  f16_t* BtL   = (f16_t*)take((size_t)NQKV * DD * sizeof(f16_t));
  f16_t* W1T   = (f16_t*)take((size_t)NHID * DD * sizeof(f16_t));
  f16_t* W2T   = (f16_t*)take((size_t)DD * NHID * sizeof(f16_t));
  float* biasC = (float*)take((size_t)NQKV * sizeof(float));
  f16_t* hbuf  = (f16_t*)take((size_t)MROWS * DD * sizeof(f16_t));   // h_hi, then h2
  char*  big   = take((size_t)MROWS * NQKV * sizeof(float));         // WfAll, qkvF, mlp1
  float2* Scum = (float2*)take((size_t)MROWS * FPAD * sizeof(float2));
  float* x2    = (float*)take((size_t)MROWS * DD * sizeof(float));
  float2* Tch  = (float2*)take((size_t)NB * NCHUNK * FBINS * sizeof(float2));
  // time-disjoint aliases:
  float* WfAll   = (float*)big;   // consumed by transposes before gemm writes qkvF
  float* qkv_f   = (float*)big;   // bins from split GEMM (alive through unbind)
  f16_t* mlp1    = (f16_t*)big;   // gelu output, after qkv_f dead
  f16_t* hlo     = (f16_t*)x2;    // LN1 lo; dead before unbind writes x2

  // 1. FFT weight rows (fp32) -> WfAll[p][k][1056]
  wfft_k<<<3 * DD, 256, 0, stream>>>(Wq, Wk, Wv, WfAll);
  // 2. transpose + hi/lo split -> Bt (3*1056 x 1024), then zero pad rows
  for (int pp = 0; pp < 3; ++pp)
    transpose_cast2_k<<<dim3(WFP / 32, DD / 32), 256, 0, stream>>>(
        WfAll + (size_t)pp * DD * WFP,
        BtH + (size_t)pp * WFP * DD,
        BtL + (size_t)pp * WFP * DD, DD, WFP);
  zeropad_bt_k<<<128, 256, 0, stream>>>(BtH, BtL);
  // 3. FFT biases -> biasC
  bfft_k<<<4, 256, 0, stream>>>(bq, bk, bv, biasC);
  // 4. MLP weights -> transposed fp16
  transpose_cast_k<<<dim3(128, 32), 256, 0, stream>>>(W1, W1T, DD, NHID);
  transpose_cast_k<<<dim3(32, 128), 256, 0, stream>>>(W2, W2T, NHID, DD);

  // 5. h = LN1(x) -> hi/lo fp16 pair
  ln_cast2_k<<<MROWS, 256, 0, stream>>>(x, ln1_g, ln1_b, hbuf, hlo);

  // 6. Fourier bins directly: qkv_f = h @ rfft_rows(W)^T + rfft(bias)
  gemm_split_k<<<(NQKV / 128) * (MROWS / 128), 256, 0, stream>>>(
      hbuf, hlo, BtH, BtL, biasC, qkv_f, MROWS, NQKV, DD);

  // 7. causal prefix sum over S (P = unit(Fk).*unit(Fv) computed inline)
  scan_pass1_k<<<NB * NCHUNK, 256, 0, stream>>>(qkv_f, Tch);
  scan_pass2_k<<<(NB * FBINS + 255) / 256, 256, 0, stream>>>(Tch);
  scan_pass3_k<<<NB * NCHUNK, 256, 0, stream>>>(qkv_f, Tch, Scum);

  // 8. unbind (Fq normalized inline) + residual + LN2
  unbind_ln2_k<<<MROWS, 256, 0, stream>>>(Scum, qkv_f, x, x2, hbuf, ln2_g, ln2_b);

  // 9. mlp1 = gelu(h2 @ W1 + b1)   (qkv_f dead -> reuse big as mlp1)
  gemm_bt_k<1><<<dim3(NHID / 128, MROWS / 128), 256, 0, stream>>>(
      hbuf, W1T, b1, nullptr, nullptr, mlp1, MROWS, NHID, DD);

  // 10. out = x2 + mlp1 @ W2 + b2
  gemm_bt_k<2><<<dim3(DD / 128, MROWS / 128), 256, 0, stream>>>(
      mlp1, W2T, b2, x2, out, nullptr, MROWS, DD, NHID);
}

// Round 6
// 570.267 us; speedup vs baseline: 1.4497x; 1.1632x over previous
//
#include <hip/hip_runtime.h>
#include <cstdint>
#include <cstddef>

// Problem constants (B=4, S=2048, D=1024)
#define DD 1024
#define SSEQ 2048
#define NB 4
#define MROWS 8192          // B*S
#define FBINS 513           // rfft bins for N=1024
#define FPAD 520            // padded row stride for Scum buffer
#define WFP 1152            // per-projection padded fp32 column count (9 tiles)
#define NQKV 3456           // 3 * WFP = 27 tiles of 128
#define NHID 4096
#define NCHUNK 64           // scan chunks over S
#define SCHUNK 32           // S per chunk

typedef _Float16 f16_t;
typedef _Float16 f16x8 __attribute__((ext_vector_type(8)));
typedef float f32x4 __attribute__((ext_vector_type(4)));

__device__ __forceinline__ float2 cmul(float2 a, float2 b) {
  return make_float2(a.x * b.x - a.y * b.y, a.x * b.y + a.y * b.x);
}

// Async global->LDS 16B copy (m97: width=16 emits global_load_lds_dwordx4).
__device__ __forceinline__ void async_cp16(const void* g, void* l) {
  __builtin_amdgcn_global_load_lds(
      (const __attribute__((address_space(1))) void*)g,
      (__attribute__((address_space(3))) void*)l, 16, 0, 0);
}

// 1024-pt complex FFT over LDS ping-pong buffers; result lands back in bufA.
__device__ __forceinline__ void fft1024(float2* bufA, float2* bufB,
                                        const float2* tw, int tid) {
  float2* s = bufA;
  float2* d = bufB;
  for (int m = 1; m < 1024; m <<= 1) {
#pragma unroll
    for (int r2 = 0; r2 < 2; ++r2) {
      int u = tid + r2 * 256;
      int k = u & (m - 1);
      int jm = u - k;
      float2 c0 = s[u];
      float2 c1 = s[u + 512];
      float2 wt = tw[jm];
      float2 su = make_float2(c0.x + c1.x, c0.y + c1.y);
      float2 df = make_float2(c0.x - c1.x, c0.y - c1.y);
      float2 pr = cmul(wt, df);
      d[2 * jm + k] = su;
      d[2 * jm + k + m] = pr;
    }
    __syncthreads();
    float2* tmp = s; s = d; d = tmp;
  }
}

// ---------------------------------------------------------------------------
// Weight-row FFT: WfAll[p][k][j] = interleaved Re/Im of rfft(W_p[k, :]).
// j in [0,1026) data, [1026,1152) zero pad.
// ---------------------------------------------------------------------------
__global__ __launch_bounds__(256) void wfft_k(
    const float* __restrict__ Wq, const float* __restrict__ Wk,
    const float* __restrict__ Wv, float* __restrict__ WfAll) {
  __shared__ float2 tw[512];
  __shared__ float2 bufA[1024];
  __shared__ float2 bufB[1024];
  const int tid = threadIdx.x;
  const int p = blockIdx.x >> 10, k = blockIdx.x & 1023;
  const float* W = (p == 0) ? Wq : ((p == 1) ? Wk : Wv);
  for (int t = tid; t < 512; t += 256) {
    float ang = -6.2831853071795864769f * (float)t * (1.0f / 1024.0f);
    tw[t] = make_float2(cosf(ang), sinf(ang));
  }
  const float* src = W + (size_t)k * DD;
  for (int t = tid; t < 1024; t += 256) bufA[t] = make_float2(src[t], 0.f);
  __syncthreads();
  fft1024(bufA, bufB, tw, tid);
  float* dst = WfAll + ((size_t)p * DD + k) * WFP;
  for (int t = tid; t <= 512; t += 256) {
    float2 f = bufA[t];
    dst[2 * t] = f.x;
    dst[2 * t + 1] = f.y;
  }
  for (int j = 1026 + tid; j < WFP; j += 256) dst[j] = 0.f;
}

// ---------------------------------------------------------------------------
// Bias FFT (blocks 0..2).
// ---------------------------------------------------------------------------
__global__ __launch_bounds__(256) void bfft_k(
    const float* __restrict__ bq, const float* __restrict__ bk,
    const float* __restrict__ bv, float* __restrict__ biasC) {
  __shared__ float2 tw[512];
  __shared__ float2 bufA[1024];
  __shared__ float2 bufB[1024];
  const int tid = threadIdx.x;
  const int p = blockIdx.x;
  const float* bsrc = (p == 0) ? bq : ((p == 1) ? bk : bv);
  for (int t = tid; t < 512; t += 256) {
    float ang = -6.2831853071795864769f * (float)t * (1.0f / 1024.0f);
    tw[t] = make_float2(cosf(ang), sinf(ang));
  }
  for (int t = tid; t < 1024; t += 256) bufA[t] = make_float2(bsrc[t], 0.f);
  __syncthreads();
  fft1024(bufA, bufB, tw, tid);
  float* dst = biasC + (size_t)p * WFP;
  for (int t = tid; t <= 512; t += 256) {
    float2 f = bufA[t];
    dst[2 * t] = f.x;
    dst[2 * t + 1] = f.y;
  }
  for (int j = 1026 + tid; j < WFP; j += 256) dst[j] = 0.f;
}

// ---------------------------------------------------------------------------
// Transpose + cast fp32 (K x N) -> fp16 (N x K)
// ---------------------------------------------------------------------------
__global__ __launch_bounds__(256) void transpose_cast_k(
    const float* __restrict__ W, f16_t* __restrict__ Wt, int K, int N) {
  __shared__ float tile[32][33];
  const int tx = threadIdx.x & 31, ty = threadIdx.x >> 5;  // 32 x 8
  const int n0 = blockIdx.x * 32, k0 = blockIdx.y * 32;
#pragma unroll
  for (int i = 0; i < 32; i += 8)
    tile[ty + i][tx] = W[(size_t)(k0 + ty + i) * N + n0 + tx];
  __syncthreads();
#pragma unroll
  for (int i = 0; i < 32; i += 8)
    Wt[(size_t)(n0 + ty + i) * K + k0 + tx] = (f16_t)tile[tx][ty + i];
}

// Transpose + split-cast fp32 (K x N) -> fp16 hi/lo pair (N x K)
__global__ __launch_bounds__(256) void transpose_cast2_k(
    const float* __restrict__ W, f16_t* __restrict__ WtH,
    f16_t* __restrict__ WtL, int K, int N) {
  __shared__ float tile[32][33];
  const int tx = threadIdx.x & 31, ty = threadIdx.x >> 5;  // 32 x 8
  const int n0 = blockIdx.x * 32, k0 = blockIdx.y * 32;
#pragma unroll
  for (int i = 0; i < 32; i += 8)
    tile[ty + i][tx] = W[(size_t)(k0 + ty + i) * N + n0 + tx];
  __syncthreads();
#pragma unroll
  for (int i = 0; i < 32; i += 8) {
    float val = tile[tx][ty + i];
    f16_t hi = (f16_t)val;
    f16_t lo = (f16_t)(val - (float)hi);
    size_t idx = (size_t)(n0 + ty + i) * K + k0 + tx;
    WtH[idx] = hi;
    WtL[idx] = lo;
  }
}

// ---------------------------------------------------------------------------
// LayerNorm (fp32 in) -> split fp16 hi/lo.  One block per row of 1024.
// ---------------------------------------------------------------------------
__global__ __launch_bounds__(256) void ln_cast2_k(
    const float* __restrict__ x, const float* __restrict__ g,
    const float* __restrict__ b, f16_t* __restrict__ hH,
    f16_t* __restrict__ hL) {
  const int row = blockIdx.x, tid = threadIdx.x;
  __shared__ float red[8];
  const float* xr = x + (size_t)row * DD;
  float v[4], ls = 0.f, lq = 0.f;
#pragma unroll
  for (int i = 0; i < 4; ++i) {
    v[i] = xr[i * 256 + tid];
    ls += v[i];
    lq += v[i] * v[i];
  }
#pragma unroll
  for (int o = 32; o > 0; o >>= 1) {
    ls += __shfl_down(ls, o);
    lq += __shfl_down(lq, o);
  }
  const int lane = tid & 63, w = tid >> 6;
  if (lane == 0) { red[w] = ls; red[w + 4] = lq; }
  __syncthreads();
  const float S = red[0] + red[1] + red[2] + red[3];
  const float Q = red[4] + red[5] + red[6] + red[7];
  const float mean = S * (1.f / 1024.f);
  const float var = Q * (1.f / 1024.f) - mean * mean;
  const float rs = rsqrtf(var + 1e-5f);
#pragma unroll
  for (int i = 0; i < 4; ++i) {
    int n = i * 256 + tid;
    float val = (v[i] - mean) * rs * g[n] + b[n];
    f16_t hi = (f16_t)val;
    hH[(size_t)row * DD + n] = hi;
    hL[(size_t)row * DD + n] = (f16_t)(val - (float)hi);
  }
}

// ---------------------------------------------------------------------------
// QKV GEMM (mixed precision-mode), M=8192 N=3456 K=1024.
// q-tiles (n<9):  C = (Ahi+Alo)·Bhi  -> 2 MFMA  (Blo dropped: err ~4.5e-3,
//                 0 scrambled bins expected among 4.2e6)
// k/v-tiles:      C = Ahi·Bhi        -> 1 MFMA  (k/v phase err doesn't
//                 amplify through the scan; contributes <0.01 to output)
// Async LDS staging (BK=64, 8-slot XOR swizzle), XCD snake: each XCD owns
// m-groups of 4 x all 27 n -> A fetched once/XCD, B-tile L2-resident.
// ---------------------------------------------------------------------------
__global__ __launch_bounds__(256, 2) void gemm_qkv_k(
    const f16_t* __restrict__ Ahi, const f16_t* __restrict__ Alo,
    const f16_t* __restrict__ Bhi, const float* __restrict__ bias,
    float* __restrict__ outF) {
  __shared__ alignas(16) f16_t AsH[128 * 64];
  __shared__ alignas(16) f16_t AsL[128 * 64];
  __shared__ alignas(16) f16_t BsH[128 * 64];
  const int tid = threadIdx.x;
  const int lane = tid & 63;
  const int w = tid >> 6;
  const int wm = w >> 1, wn = w & 1;

  // snake: s bijective over 1728; g in [0,16), n in [0,27), m = g*4 + mi
  const int lin = blockIdx.x;
  const int s = (lin & 7) * 216 + (lin >> 3);
  const int g = s / 108;
  const int r = s % 108;
  const int n = r >> 2;
  const int m0 = g * 4 + (r & 3);
  const int bn = n * 128;
  const int bm = m0 * 128;
  const bool qmode = (n < 9);

  f32x4 acc[4][4];
#pragma unroll
  for (int i = 0; i < 4; ++i)
#pragma unroll
    for (int j = 0; j < 4; ++j) acc[i][j] = (f32x4){0.f, 0.f, 0.f, 0.f};

  const int srow = lane >> 3;           // 0..7 within 8-row chunk
  const int slot = lane & 7;

  for (int kt = 0; kt < 1024; kt += 64) {
#pragma unroll
    for (int i = 0; i < 4; ++i) {
      const int rb = (i * 4 + w) * 8;
      const int row = rb + srow;
      const int gg = (slot - (row & 7)) & 7;
      size_t ga = (size_t)(bm + row) * 1024 + kt + gg * 8;
      size_t gb = (size_t)(bn + row) * 1024 + kt + gg * 8;
      async_cp16(Ahi + ga, &AsH[rb * 64]);
      if (qmode) async_cp16(Alo + ga, &AsL[rb * 64]);
      async_cp16(Bhi + gb, &BsH[rb * 64]);
    }
    __syncthreads();
#pragma unroll
    for (int ks = 0; ks < 2; ++ks) {
      const int cgbase = ks * 4 + (lane >> 4);
      f16x8 ah[4], bh[4];
#pragma unroll
      for (int mt = 0; mt < 4; ++mt) {
        int m = wm * 64 + mt * 16 + (lane & 15);
        int sl = (cgbase + (m & 7)) & 7;
        ah[mt] = *(const f16x8*)(&AsH[m * 64 + sl * 8]);
      }
#pragma unroll
      for (int nt = 0; nt < 4; ++nt) {
        int nn = wn * 64 + nt * 16 + (lane & 15);
        int sl = (cgbase + (nn & 7)) & 7;
        bh[nt] = *(const f16x8*)(&BsH[nn * 64 + sl * 8]);
      }
#pragma unroll
      for (int mt = 0; mt < 4; ++mt)
#pragma unroll
        for (int nt = 0; nt < 4; ++nt)
          acc[mt][nt] = __builtin_amdgcn_mfma_f32_16x16x32_f16(
              ah[mt], bh[nt], acc[mt][nt], 0, 0, 0);
      if (qmode) {
        f16x8 al[4];
#pragma unroll
        for (int mt = 0; mt < 4; ++mt) {
          int m = wm * 64 + mt * 16 + (lane & 15);
          int sl = (cgbase + (m & 7)) & 7;
          al[mt] = *(const f16x8*)(&AsL[m * 64 + sl * 8]);
        }
#pragma unroll
        for (int mt = 0; mt < 4; ++mt)
#pragma unroll
          for (int nt = 0; nt < 4; ++nt)
            acc[mt][nt] = __builtin_amdgcn_mfma_f32_16x16x32_f16(
                al[mt], bh[nt], acc[mt][nt], 0, 0, 0);
      }
    }
    __syncthreads();
  }

  const int q = lane >> 4;
  const int cn = lane & 15;
#pragma unroll
  for (int mt = 0; mt < 4; ++mt) {
#pragma unroll
    for (int nt = 0; nt < 4; ++nt) {
      const int gcol = bn + wn * 64 + nt * 16 + cn;
      const float bv = bias[gcol];
      const int grow0 = bm + wm * 64 + mt * 16 + q * 4;
#pragma unroll
      for (int i = 0; i < 4; ++i) {
        size_t idx = (size_t)(grow0 + i) * NQKV + gcol;
        outF[idx] = acc[mt][nt][i] + bv;
      }
    }
  }
}

// ---------------------------------------------------------------------------
// Plain fp16 GEMM, async staging.  EPI 1: gelu->fp16, 2-D grid (N=4096:
// n%8 XCD mapping already L2-friendly).  EPI 2: +resid->fp32, 1-D grid with
// XCD snake (m-groups of 2 x all 8 n) to stop per-XCD full-A streaming.
// ---------------------------------------------------------------------------
template <int EPI>
__global__ __launch_bounds__(256, 2) void gemm_bt_k(
    const f16_t* __restrict__ A, const f16_t* __restrict__ Bt,
    const float* __restrict__ bias, const float* __restrict__ resid,
    float* __restrict__ outF, f16_t* __restrict__ outH, int M, int N, int K) {
  __shared__ alignas(16) f16_t As[128 * 64];
  __shared__ alignas(16) f16_t Bs[128 * 64];
  const int tid = threadIdx.x;
  const int lane = tid & 63;
  const int w = tid >> 6;
  const int wm = w >> 1, wn = w & 1;
  int bm, bn;
  if (EPI == 2) {
    // snake over ntn = N/128 (8), ntm = M/128 (64); G = 2
    const int ntn = N >> 7;
    const int per = ((N >> 7) * (M >> 7)) >> 3;
    const int s = ((int)blockIdx.x & 7) * per + ((int)blockIdx.x >> 3);
    const int half = ntn * 2;
    const int g = s / half;
    const int r = s % half;
    bn = (r >> 1) * 128;
    bm = (g * 2 + (r & 1)) * 128;
  } else {
    bm = blockIdx.y * 128;
    bn = blockIdx.x * 128;
  }

  f32x4 acc[4][4];
#pragma unroll
  for (int i = 0; i < 4; ++i)
#pragma unroll
    for (int j = 0; j < 4; ++j) acc[i][j] = (f32x4){0.f, 0.f, 0.f, 0.f};

  const int srow = lane >> 3;
  const int slot = lane & 7;

  for (int kt = 0; kt < K; kt += 64) {
#pragma unroll
    for (int i = 0; i < 4; ++i) {
      const int rb = (i * 4 + w) * 8;
      const int row = rb + srow;
      const int gg = (slot - (row & 7)) & 7;
      const f16_t* ga = A + (size_t)(bm + row) * K + kt + gg * 8;
      const f16_t* gb = Bt + (size_t)(bn + row) * K + kt + gg * 8;
      async_cp16(ga, &As[rb * 64]);
      async_cp16(gb, &Bs[rb * 64]);
    }
    __syncthreads();
#pragma unroll
    for (int ks = 0; ks < 2; ++ks) {
      const int cgbase = ks * 4 + (lane >> 4);
      f16x8 af[4], bfv[4];
#pragma unroll
      for (int mt = 0; mt < 4; ++mt) {
        int m = wm * 64 + mt * 16 + (lane & 15);
        int sl = (cgbase + (m & 7)) & 7;
        af[mt] = *(const f16x8*)(&As[m * 64 + sl * 8]);
      }
#pragma unroll
      for (int nt = 0; nt < 4; ++nt) {
        int nn = wn * 64 + nt * 16 + (lane & 15);
        int sl = (cgbase + (nn & 7)) & 7;
        bfv[nt] = *(const f16x8*)(&Bs[nn * 64 + sl * 8]);
      }
#pragma unroll
      for (int mt = 0; mt < 4; ++mt)
#pragma unroll
        for (int nt = 0; nt < 4; ++nt)
          acc[mt][nt] = __builtin_amdgcn_mfma_f32_16x16x32_f16(
              af[mt], bfv[nt], acc[mt][nt], 0, 0, 0);
    }
    __syncthreads();
  }

  const int q = lane >> 4;
  const int cn = lane & 15;
#pragma unroll
  for (int mt = 0; mt < 4; ++mt) {
#pragma unroll
    for (int nt = 0; nt < 4; ++nt) {
      const int gcol = bn + wn * 64 + nt * 16 + cn;
      const float bv = bias[gcol];
      const int grow0 = bm + wm * 64 + mt * 16 + q * 4;
#pragma unroll
      for (int i = 0; i < 4; ++i) {
        float val = acc[mt][nt][i] + bv;
        size_t idx = (size_t)(grow0 + i) * N + gcol;
        if (EPI == 1) {
          float ge = 0.5f * val * (1.0f + erff(val * 0.70710678118654752f));
          outH[idx] = (f16_t)ge;
        } else {
          outF[idx] = val + resid[idx];
        }
      }
    }
  }
}

// ---------------------------------------------------------------------------
// Inline normalize helpers reading raw bins from qkv_f rows (1728 float2).
// q at [f], k at [576+f], v at [1152+f].
// ---------------------------------------------------------------------------
__device__ __forceinline__ float2 unitc(float2 a) {
  float inv = 1.0f / fmaxf(sqrtf(a.x * a.x + a.y * a.y), 1e-8f);
  return make_float2(a.x * inv, a.y * inv);
}
__device__ __forceinline__ float2 bind_bin(const float2* r, int f) {
  float2 kn = unitc(r[576 + f]);
  float2 vn = unitc(r[1152 + f]);
  return cmul(kn, vn);
}

// ---------------------------------------------------------------------------
// 3-pass parallel prefix sum over S per (batch, bin), P computed inline.
// ---------------------------------------------------------------------------
__global__ __launch_bounds__(256) void scan_pass1_k(
    const float* __restrict__ qkvF, float2* __restrict__ T) {
  const int b = blockIdx.x >> 6, sc = blockIdx.x & 63;
  const int s0 = sc * SCHUNK;
  const float2* base = (const float2*)(qkvF + ((size_t)(b * SSEQ + s0)) * NQKV);
  for (int f = threadIdx.x; f < FBINS; f += 256) {
    float2 acc = make_float2(0.f, 0.f);
    const float2* r = base;
    for (int i = 0; i < SCHUNK; ++i) {
      float2 pv = bind_bin(r, f);
      acc.x += pv.x; acc.y += pv.y;
      r += NQKV / 2;
    }
    T[((size_t)b * NCHUNK + sc) * FBINS + f] = acc;
  }
}

__global__ void scan_pass2_k(float2* __restrict__ T) {
  const int idx = blockIdx.x * 256 + threadIdx.x;
  if (idx >= NB * FBINS) return;
  const int b = idx / FBINS, f = idx % FBINS;
  float2 acc = make_float2(0.f, 0.f);
  for (int sc = 0; sc < NCHUNK; ++sc) {
    size_t a = ((size_t)b * NCHUNK + sc) * FBINS + f;
    float2 v = T[a];
    T[a] = acc;
    acc.x += v.x; acc.y += v.y;
  }
}

__global__ __launch_bounds__(256) void scan_pass3_k(
    const float* __restrict__ qkvF, const float2* __restrict__ T,
    float2* __restrict__ Scum) {
  const int b = blockIdx.x >> 6, sc = blockIdx.x & 63;
  const int s0 = sc * SCHUNK;
  const float2* base = (const float2*)(qkvF + ((size_t)(b * SSEQ + s0)) * NQKV);
  for (int f = threadIdx.x; f < FBINS; f += 256) {
    float2 acc = T[((size_t)b * NCHUNK + sc) * FBINS + f];
    const float2* r = base;
    size_t orow = ((size_t)(b * SSEQ + s0)) * FPAD + f;
    for (int i = 0; i < SCHUNK; ++i) {
      float2 pv = bind_bin(r, f);
      acc.x += pv.x; acc.y += pv.y;
      Scum[orow] = acc;
      r += NQKV / 2;
      orow += FPAD;
    }
  }
}

// ---------------------------------------------------------------------------
// Per-row: Fq = unit(q bins); M = Scum .* conj(Fq); mixed = irfft(M);
// x2 = x + mixed; h2 = LN2(x2) -> fp16.
// ---------------------------------------------------------------------------
__global__ __launch_bounds__(256) void unbind_ln2_k(
    const float2* __restrict__ Scum, const float* __restrict__ qkvF,
    const float* __restrict__ x, float* __restrict__ x2out,
    f16_t* __restrict__ h2, const float* __restrict__ g2,
    const float* __restrict__ b2) {
  __shared__ float2 tw[512];
  __shared__ float2 bufA[1024];
  __shared__ float2 bufB[1024];
  __shared__ float red[8];
  const int tid = threadIdx.x;
  const int row = blockIdx.x;

  for (int t = tid; t < 512; t += 256) {
    float ang = 6.2831853071795864769f * (float)t * (1.0f / 1024.0f);
    tw[t] = make_float2(cosf(ang), sinf(ang));  // inverse twiddles
  }
  const float2* qrow = (const float2*)(qkvF + (size_t)row * NQKV);
  for (int t = tid; t <= 512; t += 256) {
    float2 sc = Scum[(size_t)row * FPAD + t];
    float2 fq = unitc(qrow[t]);
    float2 Mv = make_float2(sc.x * fq.x + sc.y * fq.y, sc.y * fq.x - sc.x * fq.y);
    bufA[t] = Mv;
    if (t >= 1 && t < 512) bufA[1024 - t] = make_float2(Mv.x, -Mv.y);
  }
  __syncthreads();
  fft1024(bufA, bufB, tw, tid);

  const float* xr = x + (size_t)row * DD;
  float v[4], ls = 0.f, lq = 0.f;
#pragma unroll
  for (int i = 0; i < 4; ++i) {
    int n = i * 256 + tid;
    float val = xr[n] + bufA[n].x * (1.0f / 1024.0f);
    x2out[(size_t)row * DD + n] = val;
    v[i] = val;
    ls += val;
    lq += val * val;
  }
#pragma unroll
  for (int o = 32; o > 0; o >>= 1) {
    ls += __shfl_down(ls, o);
    lq += __shfl_down(lq, o);
  }
  const int lane = tid & 63, w = tid >> 6;
  if (lane == 0) { red[w] = ls; red[w + 4] = lq; }
  __syncthreads();
  const float S = red[0] + red[1] + red[2] + red[3];
  const float Q = red[4] + red[5] + red[6] + red[7];
  const float mean = S * (1.f / 1024.f);
  const float var = Q * (1.f / 1024.f) - mean * mean;
  const float rs = rsqrtf(var + 1e-5f);
  f16_t* hr = h2 + (size_t)row * DD;
#pragma unroll
  for (int i = 0; i < 4; ++i) {
    int n = i * 256 + tid;
    hr[n] = (f16_t)((v[i] - mean) * rs * g2[n] + b2[n]);
  }
}

// ---------------------------------------------------------------------------
extern "C" void kernel_launch(void* const* d_in, const int* in_sizes, int n_in,
                              void* d_out, int out_size, void* d_ws,
                              size_t ws_size, hipStream_t stream) {
  const float* x     = (const float*)d_in[0];
  const float* Wq    = (const float*)d_in[1];
  const float* bq    = (const float*)d_in[2];
  const float* Wk    = (const float*)d_in[3];
  const float* bk    = (const float*)d_in[4];
  const float* Wv    = (const float*)d_in[5];
  const float* bv    = (const float*)d_in[6];
  const float* ln1_g = (const float*)d_in[7];
  const float* ln1_b = (const float*)d_in[8];
  const float* ln2_g = (const float*)d_in[9];
  const float* ln2_b = (const float*)d_in[10];
  const float* W1    = (const float*)d_in[11];
  const float* b1    = (const float*)d_in[12];
  const float* W2    = (const float*)d_in[13];
  const float* b2    = (const float*)d_in[14];
  float* out = (float*)d_out;

  char* p = (char*)d_ws;
  auto take = [&](size_t bytes) {
    char* r = p;
    p += (bytes + 255) & ~(size_t)255;
    return r;
  };
  f16_t* BtH   = (f16_t*)take((size_t)NQKV * DD * sizeof(f16_t));
  f16_t* BtL   = (f16_t*)take((size_t)NQKV * DD * sizeof(f16_t));
  f16_t* W1T   = (f16_t*)take((size_t)NHID * DD * sizeof(f16_t));
  f16_t* W2T   = (f16_t*)take((size_t)DD * NHID * sizeof(f16_t));
  float* biasC = (float*)take((size_t)NQKV * sizeof(float));
  f16_t* hbuf  = (f16_t*)take((size_t)MROWS * DD * sizeof(f16_t));   // h_hi, then h2
  char*  big   = take((size_t)MROWS * NQKV * sizeof(float));         // WfAll, qkvF, mlp1
  float2* Scum = (float2*)take((size_t)MROWS * FPAD * sizeof(float2));
  float* x2    = (float*)take((size_t)MROWS * DD * sizeof(float));
  float2* Tch  = (float2*)take((size_t)NB * NCHUNK * FBINS * sizeof(float2));
  // time-disjoint aliases:
  float* WfAll   = (float*)big;   // consumed by transposes before gemm writes qkvF
  float* qkv_f   = (float*)big;   // bins from QKV GEMM (alive through unbind)
  f16_t* mlp1    = (f16_t*)big;   // gelu output, after qkv_f dead
  f16_t* hlo     = (f16_t*)x2;    // LN1 lo; dead before unbind writes x2

  // 1. FFT weight rows (fp32) -> WfAll[p][k][1152]
  wfft_k<<<3 * DD, 256, 0, stream>>>(Wq, Wk, Wv, WfAll);
  // 2. transpose + hi/lo split -> Bt (3456 x 1024); Blo only read by q-tiles
  for (int pp = 0; pp < 3; ++pp)
    transpose_cast2_k<<<dim3(WFP / 32, DD / 32), 256, 0, stream>>>(
        WfAll + (size_t)pp * DD * WFP,
        BtH + (size_t)pp * WFP * DD,
        BtL + (size_t)pp * WFP * DD, DD, WFP);
  // 3. FFT biases -> biasC (covers all 3456 cols incl. zero pad)
  bfft_k<<<3, 256, 0, stream>>>(bq, bk, bv, biasC);
  // 4. MLP weights -> transposed fp16
  transpose_cast_k<<<dim3(128, 32), 256, 0, stream>>>(W1, W1T, DD, NHID);
  transpose_cast_k<<<dim3(32, 128), 256, 0, stream>>>(W2, W2T, NHID, DD);

  // 5. h = LN1(x) -> hi/lo fp16 pair
  ln_cast2_k<<<MROWS, 256, 0, stream>>>(x, ln1_g, ln1_b, hbuf, hlo);

  // 6. Fourier bins: qkv_f = h @ rfft_rows(W)^T + rfft(bias)
  //    q-tiles split-fp16 (2 MFMA), k/v plain (1 MFMA); XCD snake.
  gemm_qkv_k<<<(NQKV / 128) * (MROWS / 128), 256, 0, stream>>>(
      hbuf, hlo, BtH, biasC, qkv_f);

  // 7. causal prefix sum over S (P = unit(Fk).*unit(Fv) computed inline)
  scan_pass1_k<<<NB * NCHUNK, 256, 0, stream>>>(qkv_f, Tch);
  scan_pass2_k<<<(NB * FBINS + 255) / 256, 256, 0, stream>>>(Tch);
  scan_pass3_k<<<NB * NCHUNK, 256, 0, stream>>>(qkv_f, Tch, Scum);

  // 8. unbind (Fq normalized inline) + residual + LN2
  unbind_ln2_k<<<MROWS, 256, 0, stream>>>(Scum, qkv_f, x, x2, hbuf, ln2_g, ln2_b);

  // 9. mlp1 = gelu(h2 @ W1 + b1)
  gemm_bt_k<1><<<dim3(NHID / 128, MROWS / 128), 256, 0, stream>>>(
      hbuf, W1T, b1, nullptr, nullptr, mlp1, MROWS, NHID, DD);

  // 10. out = x2 + mlp1 @ W2 + b2   (1-D grid, XCD snake inside)
  gemm_bt_k<2><<<(DD / 128) * (MROWS / 128), 256, 0, stream>>>(
      mlp1, W2T, b2, x2, out, nullptr, MROWS, DD, NHID);
}

// Round 7
// 534.331 us; speedup vs baseline: 1.5472x; 1.0673x over previous
//
#include <hip/hip_runtime.h>
#include <cstdint>
#include <cstddef>

// Problem constants (B=4, S=2048, D=1024)
#define DD 1024
#define SSEQ 2048
#define NB 4
#define MROWS 8192          // B*S
#define FBINS 513           // rfft bins for N=1024
#define FPAD 520            // padded row stride for Scum buffer
#define WFP 1152            // per-projection padded fp32 column count (9 tiles)
#define NQKV 3456           // 3 * WFP = 27 tiles of 128
#define NHID 4096
#define NCHUNK 64           // scan chunks over S
#define SCHUNK 32           // S per chunk

typedef _Float16 f16_t;
typedef _Float16 f16x8 __attribute__((ext_vector_type(8)));
typedef _Float16 f16x2 __attribute__((ext_vector_type(2)));
typedef float f32x4 __attribute__((ext_vector_type(4)));

__device__ __forceinline__ float2 cmul(float2 a, float2 b) {
  return make_float2(a.x * b.x - a.y * b.y, a.x * b.y + a.y * b.x);
}

// Async global->LDS 16B copy (m97: width=16 emits global_load_lds_dwordx4).
__device__ __forceinline__ void async_cp16(const void* g, void* l) {
  __builtin_amdgcn_global_load_lds(
      (const __attribute__((address_space(1))) void*)g,
      (__attribute__((address_space(3))) void*)l, 16, 0, 0);
}

// Branchless erf-based gelu, A&S 7.1.26 (|eps_erf| <= 1.5e-7).
// gelu(v) = relu(v) - 0.5*|v| * poly(t)*exp(-z^2),  z = |v|/sqrt2.
__device__ __forceinline__ float fast_gelu(float val) {
  float av = __builtin_fabsf(val);
  float z = av * 0.70710678118654752f;
  float t = __builtin_amdgcn_rcpf(__builtin_fmaf(0.3275911f, z, 1.0f));
  float poly = t * __builtin_fmaf(t,
      __builtin_fmaf(t, __builtin_fmaf(t,
          __builtin_fmaf(t, 1.061405429f, -1.453152027f),
          1.421413741f), -0.284496736f), 0.254829592f);
  float e = __builtin_amdgcn_exp2f(z * z * -1.4426950408889634f);
  float w = poly * e;
  float r = fmaxf(val, 0.0f);
  return __builtin_fmaf(-0.5f * av, w, r);
}

// 1024-pt complex FFT over LDS ping-pong buffers; result lands back in bufA.
__device__ __forceinline__ void fft1024(float2* bufA, float2* bufB,
                                        const float2* tw, int tid) {
  float2* s = bufA;
  float2* d = bufB;
  for (int m = 1; m < 1024; m <<= 1) {
#pragma unroll
    for (int r2 = 0; r2 < 2; ++r2) {
      int u = tid + r2 * 256;
      int k = u & (m - 1);
      int jm = u - k;
      float2 c0 = s[u];
      float2 c1 = s[u + 512];
      float2 wt = tw[jm];
      float2 su = make_float2(c0.x + c1.x, c0.y + c1.y);
      float2 df = make_float2(c0.x - c1.x, c0.y - c1.y);
      float2 pr = cmul(wt, df);
      d[2 * jm + k] = su;
      d[2 * jm + k + m] = pr;
    }
    __syncthreads();
    float2* tmp = s; s = d; d = tmp;
  }
}

// 512-pt complex FFT (one butterfly per thread per stage); returns result ptr.
__device__ __forceinline__ float2* fft512(float2* bufA, float2* bufB,
                                          const float2* tw, int tid) {
  float2* s = bufA;
  float2* d = bufB;
  for (int m = 1; m < 512; m <<= 1) {
    int u = tid;
    int k = u & (m - 1);
    int jm = u - k;
    float2 c0 = s[u];
    float2 c1 = s[u + 256];
    float2 wt = tw[jm];
    float2 su = make_float2(c0.x + c1.x, c0.y + c1.y);
    float2 df = make_float2(c0.x - c1.x, c0.y - c1.y);
    float2 pr = cmul(wt, df);
    d[2 * jm + k] = su;
    d[2 * jm + k + m] = pr;
    __syncthreads();
    float2* tmp = s; s = d; d = tmp;
  }
  return s;   // 9 stages -> result in bufB
}

// ---------------------------------------------------------------------------
// Weight-row FFT: WfAll[p][k][j] = interleaved Re/Im of rfft(W_p[k, :]).
// j in [0,1026) data, [1026,1152) zero pad.
// ---------------------------------------------------------------------------
__global__ __launch_bounds__(256) void wfft_k(
    const float* __restrict__ Wq, const float* __restrict__ Wk,
    const float* __restrict__ Wv, float* __restrict__ WfAll) {
  __shared__ float2 tw[512];
  __shared__ float2 bufA[1024];
  __shared__ float2 bufB[1024];
  const int tid = threadIdx.x;
  const int p = blockIdx.x >> 10, k = blockIdx.x & 1023;
  const float* W = (p == 0) ? Wq : ((p == 1) ? Wk : Wv);
  for (int t = tid; t < 512; t += 256) {
    float ang = -6.2831853071795864769f * (float)t * (1.0f / 1024.0f);
    tw[t] = make_float2(cosf(ang), sinf(ang));
  }
  const float* src = W + (size_t)k * DD;
  for (int t = tid; t < 1024; t += 256) bufA[t] = make_float2(src[t], 0.f);
  __syncthreads();
  fft1024(bufA, bufB, tw, tid);
  float* dst = WfAll + ((size_t)p * DD + k) * WFP;
  for (int t = tid; t <= 512; t += 256) {
    float2 f = bufA[t];
    dst[2 * t] = f.x;
    dst[2 * t + 1] = f.y;
  }
  for (int j = 1026 + tid; j < WFP; j += 256) dst[j] = 0.f;
}

// ---------------------------------------------------------------------------
// Bias FFT (blocks 0..2).
// ---------------------------------------------------------------------------
__global__ __launch_bounds__(256) void bfft_k(
    const float* __restrict__ bq, const float* __restrict__ bk,
    const float* __restrict__ bv, float* __restrict__ biasC) {
  __shared__ float2 tw[512];
  __shared__ float2 bufA[1024];
  __shared__ float2 bufB[1024];
  const int tid = threadIdx.x;
  const int p = blockIdx.x;
  const float* bsrc = (p == 0) ? bq : ((p == 1) ? bk : bv);
  for (int t = tid; t < 512; t += 256) {
    float ang = -6.2831853071795864769f * (float)t * (1.0f / 1024.0f);
    tw[t] = make_float2(cosf(ang), sinf(ang));
  }
  for (int t = tid; t < 1024; t += 256) bufA[t] = make_float2(bsrc[t], 0.f);
  __syncthreads();
  fft1024(bufA, bufB, tw, tid);
  float* dst = biasC + (size_t)p * WFP;
  for (int t = tid; t <= 512; t += 256) {
    float2 f = bufA[t];
    dst[2 * t] = f.x;
    dst[2 * t + 1] = f.y;
  }
  for (int j = 1026 + tid; j < WFP; j += 256) dst[j] = 0.f;
}

// ---------------------------------------------------------------------------
// Transpose + cast fp32 (K x N) -> fp16 (N x K)
// ---------------------------------------------------------------------------
__global__ __launch_bounds__(256) void transpose_cast_k(
    const float* __restrict__ W, f16_t* __restrict__ Wt, int K, int N) {
  __shared__ float tile[32][33];
  const int tx = threadIdx.x & 31, ty = threadIdx.x >> 5;  // 32 x 8
  const int n0 = blockIdx.x * 32, k0 = blockIdx.y * 32;
#pragma unroll
  for (int i = 0; i < 32; i += 8)
    tile[ty + i][tx] = W[(size_t)(k0 + ty + i) * N + n0 + tx];
  __syncthreads();
#pragma unroll
  for (int i = 0; i < 32; i += 8)
    Wt[(size_t)(n0 + ty + i) * K + k0 + tx] = (f16_t)tile[tx][ty + i];
}

// Transpose + split-cast fp32 (K x N) -> fp16 hi/lo pair (N x K)
__global__ __launch_bounds__(256) void transpose_cast2_k(
    const float* __restrict__ W, f16_t* __restrict__ WtH,
    f16_t* __restrict__ WtL, int K, int N) {
  __shared__ float tile[32][33];
  const int tx = threadIdx.x & 31, ty = threadIdx.x >> 5;  // 32 x 8
  const int n0 = blockIdx.x * 32, k0 = blockIdx.y * 32;
#pragma unroll
  for (int i = 0; i < 32; i += 8)
    tile[ty + i][tx] = W[(size_t)(k0 + ty + i) * N + n0 + tx];
  __syncthreads();
#pragma unroll
  for (int i = 0; i < 32; i += 8) {
    float val = tile[tx][ty + i];
    f16_t hi = (f16_t)val;
    f16_t lo = (f16_t)(val - (float)hi);
    size_t idx = (size_t)(n0 + ty + i) * K + k0 + tx;
    WtH[idx] = hi;
    WtL[idx] = lo;
  }
}

// ---------------------------------------------------------------------------
// LayerNorm (fp32 in) -> split fp16 hi/lo.  One block per row of 1024.
// ---------------------------------------------------------------------------
__global__ __launch_bounds__(256) void ln_cast2_k(
    const float* __restrict__ x, const float* __restrict__ g,
    const float* __restrict__ b, f16_t* __restrict__ hH,
    f16_t* __restrict__ hL) {
  const int row = blockIdx.x, tid = threadIdx.x;
  __shared__ float red[8];
  const float* xr = x + (size_t)row * DD;
  float v[4], ls = 0.f, lq = 0.f;
#pragma unroll
  for (int i = 0; i < 4; ++i) {
    v[i] = xr[i * 256 + tid];
    ls += v[i];
    lq += v[i] * v[i];
  }
#pragma unroll
  for (int o = 32; o > 0; o >>= 1) {
    ls += __shfl_down(ls, o);
    lq += __shfl_down(lq, o);
  }
  const int lane = tid & 63, w = tid >> 6;
  if (lane == 0) { red[w] = ls; red[w + 4] = lq; }
  __syncthreads();
  const float S = red[0] + red[1] + red[2] + red[3];
  const float Q = red[4] + red[5] + red[6] + red[7];
  const float mean = S * (1.f / 1024.f);
  const float var = Q * (1.f / 1024.f) - mean * mean;
  const float rs = rsqrtf(var + 1e-5f);
#pragma unroll
  for (int i = 0; i < 4; ++i) {
    int n = i * 256 + tid;
    float val = (v[i] - mean) * rs * g[n] + b[n];
    f16_t hi = (f16_t)val;
    hH[(size_t)row * DD + n] = hi;
    hL[(size_t)row * DD + n] = (f16_t)(val - (float)hi);
  }
}

// ---------------------------------------------------------------------------
// QKV GEMM (mixed precision-mode), M=8192 N=3456 K=1024.
// q-tiles (n<9): (Ahi+Alo)*Bhi (2 MFMA).  k/v-tiles: Ahi*Bhi (1 MFMA).
// Async LDS staging (BK=64, 8-slot XOR swizzle), XCD snake.
// ---------------------------------------------------------------------------
__global__ __launch_bounds__(256, 2) void gemm_qkv_k(
    const f16_t* __restrict__ Ahi, const f16_t* __restrict__ Alo,
    const f16_t* __restrict__ Bhi, const float* __restrict__ bias,
    float* __restrict__ outF) {
  __shared__ alignas(16) f16_t AsH[128 * 64];
  __shared__ alignas(16) f16_t AsL[128 * 64];
  __shared__ alignas(16) f16_t BsH[128 * 64];
  const int tid = threadIdx.x;
  const int lane = tid & 63;
  const int w = tid >> 6;
  const int wm = w >> 1, wn = w & 1;

  const int lin = blockIdx.x;
  const int s = (lin & 7) * 216 + (lin >> 3);
  const int g = s / 108;
  const int r = s % 108;
  const int n = r >> 2;
  const int m0 = g * 4 + (r & 3);
  const int bn = n * 128;
  const int bm = m0 * 128;
  const bool qmode = (n < 9);

  f32x4 acc[4][4];
#pragma unroll
  for (int i = 0; i < 4; ++i)
#pragma unroll
    for (int j = 0; j < 4; ++j) acc[i][j] = (f32x4){0.f, 0.f, 0.f, 0.f};

  const int srow = lane >> 3;
  const int slot = lane & 7;

  for (int kt = 0; kt < 1024; kt += 64) {
#pragma unroll
    for (int i = 0; i < 4; ++i) {
      const int rb = (i * 4 + w) * 8;
      const int row = rb + srow;
      const int gg = (slot - (row & 7)) & 7;
      size_t ga = (size_t)(bm + row) * 1024 + kt + gg * 8;
      size_t gb = (size_t)(bn + row) * 1024 + kt + gg * 8;
      async_cp16(Ahi + ga, &AsH[rb * 64]);
      if (qmode) async_cp16(Alo + ga, &AsL[rb * 64]);
      async_cp16(Bhi + gb, &BsH[rb * 64]);
    }
    __syncthreads();
#pragma unroll
    for (int ks = 0; ks < 2; ++ks) {
      const int cgbase = ks * 4 + (lane >> 4);
      f16x8 ah[4], bh[4];
#pragma unroll
      for (int mt = 0; mt < 4; ++mt) {
        int m = wm * 64 + mt * 16 + (lane & 15);
        int sl = (cgbase + (m & 7)) & 7;
        ah[mt] = *(const f16x8*)(&AsH[m * 64 + sl * 8]);
      }
#pragma unroll
      for (int nt = 0; nt < 4; ++nt) {
        int nn = wn * 64 + nt * 16 + (lane & 15);
        int sl = (cgbase + (nn & 7)) & 7;
        bh[nt] = *(const f16x8*)(&BsH[nn * 64 + sl * 8]);
      }
#pragma unroll
      for (int mt = 0; mt < 4; ++mt)
#pragma unroll
        for (int nt = 0; nt < 4; ++nt)
          acc[mt][nt] = __builtin_amdgcn_mfma_f32_16x16x32_f16(
              ah[mt], bh[nt], acc[mt][nt], 0, 0, 0);
      if (qmode) {
        f16x8 al[4];
#pragma unroll
        for (int mt = 0; mt < 4; ++mt) {
          int m = wm * 64 + mt * 16 + (lane & 15);
          int sl = (cgbase + (m & 7)) & 7;
          al[mt] = *(const f16x8*)(&AsL[m * 64 + sl * 8]);
        }
#pragma unroll
        for (int mt = 0; mt < 4; ++mt)
#pragma unroll
          for (int nt = 0; nt < 4; ++nt)
            acc[mt][nt] = __builtin_amdgcn_mfma_f32_16x16x32_f16(
                al[mt], bh[nt], acc[mt][nt], 0, 0, 0);
      }
    }
    __syncthreads();
  }

  const int q = lane >> 4;
  const int cn = lane & 15;
#pragma unroll
  for (int mt = 0; mt < 4; ++mt) {
#pragma unroll
    for (int nt = 0; nt < 4; ++nt) {
      const int gcol = bn + wn * 64 + nt * 16 + cn;
      const float bv = bias[gcol];
      const int grow0 = bm + wm * 64 + mt * 16 + q * 4;
#pragma unroll
      for (int i = 0; i < 4; ++i) {
        size_t idx = (size_t)(grow0 + i) * NQKV + gcol;
        outF[idx] = acc[mt][nt][i] + bv;
      }
    }
  }
}

// ---------------------------------------------------------------------------
// Plain fp16 GEMM, async staging.  EPI 1: fast-gelu->fp16 (2-D grid).
// EPI 2: +resid->fp32 (1-D grid, XCD snake).
// ---------------------------------------------------------------------------
template <int EPI>
__global__ __launch_bounds__(256, 2) void gemm_bt_k(
    const f16_t* __restrict__ A, const f16_t* __restrict__ Bt,
    const float* __restrict__ bias, const float* __restrict__ resid,
    float* __restrict__ outF, f16_t* __restrict__ outH, int M, int N, int K) {
  __shared__ alignas(16) f16_t As[128 * 64];
  __shared__ alignas(16) f16_t Bs[128 * 64];
  const int tid = threadIdx.x;
  const int lane = tid & 63;
  const int w = tid >> 6;
  const int wm = w >> 1, wn = w & 1;
  int bm, bn;
  if (EPI == 2) {
    const int ntn = N >> 7;
    const int per = ((N >> 7) * (M >> 7)) >> 3;
    const int s = ((int)blockIdx.x & 7) * per + ((int)blockIdx.x >> 3);
    const int half = ntn * 2;
    const int g = s / half;
    const int r = s % half;
    bn = (r >> 1) * 128;
    bm = (g * 2 + (r & 1)) * 128;
  } else {
    bm = blockIdx.y * 128;
    bn = blockIdx.x * 128;
  }

  f32x4 acc[4][4];
#pragma unroll
  for (int i = 0; i < 4; ++i)
#pragma unroll
    for (int j = 0; j < 4; ++j) acc[i][j] = (f32x4){0.f, 0.f, 0.f, 0.f};

  const int srow = lane >> 3;
  const int slot = lane & 7;

  for (int kt = 0; kt < K; kt += 64) {
#pragma unroll
    for (int i = 0; i < 4; ++i) {
      const int rb = (i * 4 + w) * 8;
      const int row = rb + srow;
      const int gg = (slot - (row & 7)) & 7;
      const f16_t* ga = A + (size_t)(bm + row) * K + kt + gg * 8;
      const f16_t* gb = Bt + (size_t)(bn + row) * K + kt + gg * 8;
      async_cp16(ga, &As[rb * 64]);
      async_cp16(gb, &Bs[rb * 64]);
    }
    __syncthreads();
#pragma unroll
    for (int ks = 0; ks < 2; ++ks) {
      const int cgbase = ks * 4 + (lane >> 4);
      f16x8 af[4], bfv[4];
#pragma unroll
      for (int mt = 0; mt < 4; ++mt) {
        int m = wm * 64 + mt * 16 + (lane & 15);
        int sl = (cgbase + (m & 7)) & 7;
        af[mt] = *(const f16x8*)(&As[m * 64 + sl * 8]);
      }
#pragma unroll
      for (int nt = 0; nt < 4; ++nt) {
        int nn = wn * 64 + nt * 16 + (lane & 15);
        int sl = (cgbase + (nn & 7)) & 7;
        bfv[nt] = *(const f16x8*)(&Bs[nn * 64 + sl * 8]);
      }
#pragma unroll
      for (int mt = 0; mt < 4; ++mt)
#pragma unroll
        for (int nt = 0; nt < 4; ++nt)
          acc[mt][nt] = __builtin_amdgcn_mfma_f32_16x16x32_f16(
              af[mt], bfv[nt], acc[mt][nt], 0, 0, 0);
    }
    __syncthreads();
  }

  const int q = lane >> 4;
  const int cn = lane & 15;
#pragma unroll
  for (int mt = 0; mt < 4; ++mt) {
#pragma unroll
    for (int nt = 0; nt < 4; ++nt) {
      const int gcol = bn + wn * 64 + nt * 16 + cn;
      const float bv = bias[gcol];
      const int grow0 = bm + wm * 64 + mt * 16 + q * 4;
#pragma unroll
      for (int i = 0; i < 4; ++i) {
        float val = acc[mt][nt][i] + bv;
        size_t idx = (size_t)(grow0 + i) * N + gcol;
        if (EPI == 1) {
          outH[idx] = (f16_t)fast_gelu(val);
        } else {
          outF[idx] = val + resid[idx];
        }
      }
    }
  }
}

// ---------------------------------------------------------------------------
// Inline normalize helpers reading raw bins from qkv_f rows (1728 float2).
// q at [f], k at [576+f], v at [1152+f].
// ---------------------------------------------------------------------------
__device__ __forceinline__ float2 unitc(float2 a) {
  float inv = 1.0f / fmaxf(sqrtf(a.x * a.x + a.y * a.y), 1e-8f);
  return make_float2(a.x * inv, a.y * inv);
}
__device__ __forceinline__ float2 bind_bin(const float2* r, int f) {
  float2 kn = unitc(r[576 + f]);
  float2 vn = unitc(r[1152 + f]);
  return cmul(kn, vn);
}

// ---------------------------------------------------------------------------
// 3-pass parallel prefix sum over S per (batch, bin), P computed inline.
// pass1/pass3 grids: NB * NCHUNK * 2 (f-split for occupancy).
// ---------------------------------------------------------------------------
__global__ __launch_bounds__(256) void scan_pass1_k(
    const float* __restrict__ qkvF, float2* __restrict__ T) {
  const int bid = blockIdx.x;
  const int sc = bid & 63;
  const int fh = (bid >> 6) & 1;
  const int b = bid >> 7;
  const int s0 = sc * SCHUNK;
  const float2* base = (const float2*)(qkvF + ((size_t)(b * SSEQ + s0)) * NQKV);
  for (int f = fh * 256 + threadIdx.x; f < FBINS; f += 512) {
    float2 acc = make_float2(0.f, 0.f);
    const float2* r = base;
    for (int i = 0; i < SCHUNK; ++i) {
      float2 pv = bind_bin(r, f);
      acc.x += pv.x; acc.y += pv.y;
      r += NQKV / 2;
    }
    T[((size_t)b * NCHUNK + sc) * FBINS + f] = acc;
  }
}

__global__ void scan_pass2_k(float2* __restrict__ T) {
  const int idx = blockIdx.x * 256 + threadIdx.x;
  if (idx >= NB * FBINS) return;
  const int b = idx / FBINS, f = idx % FBINS;
  float2 acc = make_float2(0.f, 0.f);
  for (int sc = 0; sc < NCHUNK; ++sc) {
    size_t a = ((size_t)b * NCHUNK + sc) * FBINS + f;
    float2 v = T[a];
    T[a] = acc;
    acc.x += v.x; acc.y += v.y;
  }
}

__global__ __launch_bounds__(256) void scan_pass3_k(
    const float* __restrict__ qkvF, const float2* __restrict__ T,
    float2* __restrict__ Scum) {
  const int bid = blockIdx.x;
  const int sc = bid & 63;
  const int fh = (bid >> 6) & 1;
  const int b = bid >> 7;
  const int s0 = sc * SCHUNK;
  const float2* base = (const float2*)(qkvF + ((size_t)(b * SSEQ + s0)) * NQKV);
  for (int f = fh * 256 + threadIdx.x; f < FBINS; f += 512) {
    float2 acc = T[((size_t)b * NCHUNK + sc) * FBINS + f];
    const float2* r = base;
    size_t orow = ((size_t)(b * SSEQ + s0)) * FPAD + f;
    for (int i = 0; i < SCHUNK; ++i) {
      float2 pv = bind_bin(r, f);
      acc.x += pv.x; acc.y += pv.y;
      Scum[orow] = acc;
      r += NQKV / 2;
      orow += FPAD;
    }
  }
}

// ---------------------------------------------------------------------------
// Per-row: Fq = unit(q bins); M = Scum .* conj(Fq); mixed = irfft(M) via
// packed real inverse (512-pt complex iFFT + E/O pre-twiddle);
// x2 = x + mixed; h2 = LN2(x2) -> fp16.
//   E[t] = 0.5(M[t]+conj(M[512-t]));  O[t] = 0.5 e^{+2pi i t/1024}(M[t]-conj(M[512-t]))
//   Z[t] = E + iO;  z = (1/512) IDFT_512(Z);  x[2n]=Re z[n], x[2n+1]=Im z[n]
// ---------------------------------------------------------------------------
__global__ __launch_bounds__(256) void unbind_ln2_k(
    const float2* __restrict__ Scum, const float* __restrict__ qkvF,
    const float* __restrict__ x, float* __restrict__ x2out,
    f16_t* __restrict__ h2, const float* __restrict__ g2,
    const float* __restrict__ b2) {
  __shared__ float2 tw[256];     // e^{+2pi i t/512}
  __shared__ float2 Marr[513];
  __shared__ float2 bufA[512];
  __shared__ float2 bufB[512];
  __shared__ float red[8];
  const int tid = threadIdx.x;
  const int row = blockIdx.x;

  {
    float ang = 6.2831853071795864769f * (float)tid * (1.0f / 512.0f);
    tw[tid] = make_float2(cosf(ang), sinf(ang));
  }
  const float2* qrow = (const float2*)(qkvF + (size_t)row * NQKV);
  for (int t = tid; t <= 512; t += 256) {
    float2 sc = Scum[(size_t)row * FPAD + t];
    float2 fq = unitc(qrow[t]);
    Marr[t] = make_float2(sc.x * fq.x + sc.y * fq.y, sc.y * fq.x - sc.x * fq.y);
  }
  __syncthreads();
  // build Z into bufA
#pragma unroll
  for (int rr = 0; rr < 2; ++rr) {
    int t = tid + rr * 256;
    float2 a = Marr[t];
    float2 b = Marr[512 - t];
    float2 E = make_float2(0.5f * (a.x + b.x), 0.5f * (a.y - b.y));
    float2 Dd = make_float2(0.5f * (a.x - b.x), 0.5f * (a.y + b.y));
    float ang = 6.2831853071795864769f * (float)t * (1.0f / 1024.0f);
    float cw = cosf(ang), sw = sinf(ang);
    float2 O = make_float2(cw * Dd.x - sw * Dd.y, cw * Dd.y + sw * Dd.x);
    bufA[t] = make_float2(E.x - O.y, E.y + O.x);
  }
  __syncthreads();
  float2* res = fft512(bufA, bufB, tw, tid);

  const float* xr = x + (size_t)row * DD;
  float v[2][2];
  float ls = 0.f, lq = 0.f;
#pragma unroll
  for (int rr = 0; rr < 2; ++rr) {
    int n = tid + rr * 256;
    float2 z = res[n];
    float2 xv = *(const float2*)(xr + 2 * n);
    float v0 = xv.x + z.x * (1.0f / 512.0f);
    float v1 = xv.y + z.y * (1.0f / 512.0f);
    *(float2*)(x2out + (size_t)row * DD + 2 * n) = make_float2(v0, v1);
    v[rr][0] = v0; v[rr][1] = v1;
    ls += v0 + v1;
    lq += v0 * v0 + v1 * v1;
  }
#pragma unroll
  for (int o = 32; o > 0; o >>= 1) {
    ls += __shfl_down(ls, o);
    lq += __shfl_down(lq, o);
  }
  const int lane = tid & 63, w = tid >> 6;
  if (lane == 0) { red[w] = ls; red[w + 4] = lq; }
  __syncthreads();
  const float S = red[0] + red[1] + red[2] + red[3];
  const float Q = red[4] + red[5] + red[6] + red[7];
  const float mean = S * (1.f / 1024.f);
  const float var = Q * (1.f / 1024.f) - mean * mean;
  const float rs = rsqrtf(var + 1e-5f);
  f16_t* hr = h2 + (size_t)row * DD;
#pragma unroll
  for (int rr = 0; rr < 2; ++rr) {
    int n = tid + rr * 256;
    float2 gv = *(const float2*)(g2 + 2 * n);
    float2 bv = *(const float2*)(b2 + 2 * n);
    f16x2 hp;
    hp[0] = (f16_t)((v[rr][0] - mean) * rs * gv.x + bv.x);
    hp[1] = (f16_t)((v[rr][1] - mean) * rs * gv.y + bv.y);
    *(f16x2*)(hr + 2 * n) = hp;
  }
}

// ---------------------------------------------------------------------------
extern "C" void kernel_launch(void* const* d_in, const int* in_sizes, int n_in,
                              void* d_out, int out_size, void* d_ws,
                              size_t ws_size, hipStream_t stream) {
  const float* x     = (const float*)d_in[0];
  const float* Wq    = (const float*)d_in[1];
  const float* bq    = (const float*)d_in[2];
  const float* Wk    = (const float*)d_in[3];
  const float* bk    = (const float*)d_in[4];
  const float* Wv    = (const float*)d_in[5];
  const float* bv    = (const float*)d_in[6];
  const float* ln1_g = (const float*)d_in[7];
  const float* ln1_b = (const float*)d_in[8];
  const float* ln2_g = (const float*)d_in[9];
  const float* ln2_b = (const float*)d_in[10];
  const float* W1    = (const float*)d_in[11];
  const float* b1    = (const float*)d_in[12];
  const float* W2    = (const float*)d_in[13];
  const float* b2    = (const float*)d_in[14];
  float* out = (float*)d_out;

  char* p = (char*)d_ws;
  auto take = [&](size_t bytes) {
    char* r = p;
    p += (bytes + 255) & ~(size_t)255;
    return r;
  };
  f16_t* BtH   = (f16_t*)take((size_t)NQKV * DD * sizeof(f16_t));
  f16_t* BtL   = (f16_t*)take((size_t)NQKV * DD * sizeof(f16_t));
  f16_t* W1T   = (f16_t*)take((size_t)NHID * DD * sizeof(f16_t));
  f16_t* W2T   = (f16_t*)take((size_t)DD * NHID * sizeof(f16_t));
  float* biasC = (float*)take((size_t)NQKV * sizeof(float));
  f16_t* hbuf  = (f16_t*)take((size_t)MROWS * DD * sizeof(f16_t));   // h_hi, then h2
  char*  big   = take((size_t)MROWS * NQKV * sizeof(float));         // WfAll, qkvF, mlp1
  float2* Scum = (float2*)take((size_t)MROWS * FPAD * sizeof(float2));
  float* x2    = (float*)take((size_t)MROWS * DD * sizeof(float));
  float2* Tch  = (float2*)take((size_t)NB * NCHUNK * FBINS * sizeof(float2));
  // time-disjoint aliases:
  float* WfAll   = (float*)big;   // consumed by transposes before gemm writes qkvF
  float* qkv_f   = (float*)big;   // bins from QKV GEMM (alive through unbind)
  f16_t* mlp1    = (f16_t*)big;   // gelu output, after qkv_f dead
  f16_t* hlo     = (f16_t*)x2;    // LN1 lo; dead before unbind writes x2

  // 1. FFT weight rows (fp32) -> WfAll[p][k][1152]
  wfft_k<<<3 * DD, 256, 0, stream>>>(Wq, Wk, Wv, WfAll);
  // 2. transpose + hi/lo split -> Bt (3456 x 1024); Blo only read by q-tiles
  for (int pp = 0; pp < 3; ++pp)
    transpose_cast2_k<<<dim3(WFP / 32, DD / 32), 256, 0, stream>>>(
        WfAll + (size_t)pp * DD * WFP,
        BtH + (size_t)pp * WFP * DD,
        BtL + (size_t)pp * WFP * DD, DD, WFP);
  // 3. FFT biases -> biasC
  bfft_k<<<3, 256, 0, stream>>>(bq, bk, bv, biasC);
  // 4. MLP weights -> transposed fp16
  transpose_cast_k<<<dim3(128, 32), 256, 0, stream>>>(W1, W1T, DD, NHID);
  transpose_cast_k<<<dim3(32, 128), 256, 0, stream>>>(W2, W2T, NHID, DD);

  // 5. h = LN1(x) -> hi/lo fp16 pair
  ln_cast2_k<<<MROWS, 256, 0, stream>>>(x, ln1_g, ln1_b, hbuf, hlo);

  // 6. Fourier bins: qkv_f = h @ rfft_rows(W)^T + rfft(bias)
  gemm_qkv_k<<<(NQKV / 128) * (MROWS / 128), 256, 0, stream>>>(
      hbuf, hlo, BtH, biasC, qkv_f);

  // 7. causal prefix sum over S (P = unit(Fk).*unit(Fv) computed inline)
  scan_pass1_k<<<NB * NCHUNK * 2, 256, 0, stream>>>(qkv_f, Tch);
  scan_pass2_k<<<(NB * FBINS + 255) / 256, 256, 0, stream>>>(Tch);
  scan_pass3_k<<<NB * NCHUNK * 2, 256, 0, stream>>>(qkv_f, Tch, Scum);

  // 8. unbind (packed real iFFT) + residual + LN2
  unbind_ln2_k<<<MROWS, 256, 0, stream>>>(Scum, qkv_f, x, x2, hbuf, ln2_g, ln2_b);

  // 9. mlp1 = gelu(h2 @ W1 + b1)
  gemm_bt_k<1><<<dim3(NHID / 128, MROWS / 128), 256, 0, stream>>>(
      hbuf, W1T, b1, nullptr, nullptr, mlp1, MROWS, NHID, DD);

  // 10. out = x2 + mlp1 @ W2 + b2   (1-D grid, XCD snake inside)
  gemm_bt_k<2><<<(DD / 128) * (MROWS / 128), 256, 0, stream>>>(
      mlp1, W2T, b2, x2, out, nullptr, MROWS, DD, NHID);
}